// Round 13
// baseline (675.301 us; speedup 1.0000x reference)
//
#include <hip/hip_runtime.h>
#include <math.h>

#define NB 4
#define TT 16
#define NNODE 1000
#define FIN 8
#define EE 8000
#define EP 9000          // E + N self loops
#define EPAD 16384       // max padded edges (pad rows to mult of 8)
#define HID 64
#define HEADS 4
#define NL 5
#define GG (NB*TT)       // 64 graphs
#define ROWS (GG*NNODE)  // 64000
#define HCOL (HEADS*HID) // 256
#define KGI (NNODE*HID)  // 64000
#define GOUT 192         // 3*HID
#define GIK 128          // K-slice per gi-gemm block
#define KSPLIT (KGI/GIK) // 500 partial slabs
#define GOSZ (GG*GOUT)   // 12288

// ---------------- edge prep ----------------
__global__ void k_build_edges(const int* __restrict__ eidx, int* __restrict__ src_e,
                              int* __restrict__ dst_e, int* __restrict__ deg, int* __restrict__ fill) {
    int i = blockIdx.x * blockDim.x + threadIdx.x;
    if (i < EP) {
        int s, d;
        if (i < EE) { s = eidx[i]; d = eidx[EE + i]; }
        else { s = i - EE; d = i - EE; }
        src_e[i] = s; dst_e[i] = d;
    }
    if (i < NNODE) { deg[i] = 0; fill[i] = 0; }
}

__global__ void k_csr_count(const int* __restrict__ dst_e, int* __restrict__ deg) {
    int i = blockIdx.x * blockDim.x + threadIdx.x;
    if (i < EP) atomicAdd(&deg[dst_e[i]], 1);
}

// parallel inclusive scan of PADDED degrees (pad to multiple of 8)
__global__ __launch_bounds__(256) void k_csr_scan(const int* __restrict__ deg, int* __restrict__ rowptr_p) {
    __shared__ int s[1024];
    int tid = threadIdx.x;
    for (int i = tid; i < 1024; i += 256) s[i] = (i < NNODE) ? ((deg[i] + 7) & ~7) : 0;
    __syncthreads();
    for (int off = 1; off < 1024; off <<= 1) {
        int t[4];
        #pragma unroll
        for (int q = 0; q < 4; q++) { int i = tid + 256 * q; t[q] = (i >= off) ? s[i - off] : 0; }
        __syncthreads();
        #pragma unroll
        for (int q = 0; q < 4; q++) { int i = tid + 256 * q; s[i] += t[q]; }
        __syncthreads();
    }
    for (int i = tid; i < NNODE; i += 256) rowptr_p[i + 1] = s[i];
    if (tid == 0) rowptr_p[0] = 0;
}

__global__ void k_csr_fill(const int* __restrict__ src_e, const int* __restrict__ dst_e,
                           const int* __restrict__ rowptr_p, int* __restrict__ fill,
                           int* __restrict__ csr_src) {
    int i = blockIdx.x * blockDim.x + threadIdx.x;
    if (i < EP) {
        int d = dst_e[i];
        int pos = atomicAdd(&fill[d], 1);
        csr_src[rowptr_p[d] + pos] = src_e[i];
    }
}

// fill pad slots with dummy self-edges (they get alpha = 0 in the fused agg)
__global__ void k_pad_fill(const int* __restrict__ rowptr_p, const int* __restrict__ deg,
                           int* __restrict__ csr_src) {
    int n = blockIdx.x * blockDim.x + threadIdx.x;
    if (n >= NNODE) return;
    int rs = rowptr_p[n], re = rowptr_p[n + 1];
    for (int j = rs + deg[n]; j < re; j++) csr_src[j] = n;
}

// ---------------- precompute wa/wd: wa[l][j][h] = sum_c W_l[j, h*64+c] * a_src[l,h,c] ----------------
__global__ void k_wa(const float* __restrict__ Wg, const float* __restrict__ a_src,
                     const float* __restrict__ a_dst, float* __restrict__ wa, float* __restrict__ wd) {
    int t = blockIdx.x * 256 + threadIdx.x;      // 2*NL*HID*HEADS = 2560
    if (t >= 2 * NL * HID * HEADS) return;
    int kind = t >= NL * HID * HEADS;
    int u = t - kind * NL * HID * HEADS;
    int l = u >> 8;
    int rem = u & 255;
    int j = rem >> 2, hd = rem & 3;
    const float* a = (kind ? a_dst : a_src) + (size_t)l * HCOL + hd * HID;
    const float* Wl = Wg + (size_t)l * HID * HCOL + (size_t)j * HCOL + hd * HID;
    float acc = 0.f;
    #pragma unroll 8
    for (int c = 0; c < HID; c++) acc += Wl[c] * a[c];
    float* out = kind ? wd : wa;
    out[(size_t)l * HCOL + j * 4 + hd] = acc;
}

// ---------------- input projection + fused layer-0 ls/ld ----------------
__global__ void k_input_fc(const float* __restrict__ xseq, const float4* __restrict__ Win4,
                           const float4* __restrict__ b_in4, const float4* __restrict__ wa04,
                           const float4* __restrict__ wd04, float4* __restrict__ x0,
                           float4* __restrict__ ls4, float4* __restrict__ ld4) {
    int idx = blockIdx.x * 256 + threadIdx.x;   // ROWS*16 threads
    int r = idx >> 4, c4 = idx & 15;
    float4 acc = b_in4[c4];
    #pragma unroll
    for (int k = 0; k < FIN; k++) {
        float xv = xseq[r * FIN + k];
        float4 w = Win4[k * 16 + c4];
        acc.x += xv * w.x; acc.y += xv * w.y; acc.z += xv * w.z; acc.w += xv * w.w;
    }
    x0[idx] = acc;
    // ls/ld partial over this thread's 4 channels (j = c4*4..+3)
    float xr[4] = {acc.x, acc.y, acc.z, acc.w};
    float4 pls = make_float4(0.f, 0.f, 0.f, 0.f);
    float4 pld = make_float4(0.f, 0.f, 0.f, 0.f);
    #pragma unroll
    for (int jj = 0; jj < 4; jj++) {
        float4 wa_j = wa04[c4 * 4 + jj];
        float4 wd_j = wd04[c4 * 4 + jj];
        pls.x += xr[jj] * wa_j.x; pls.y += xr[jj] * wa_j.y;
        pls.z += xr[jj] * wa_j.z; pls.w += xr[jj] * wa_j.w;
        pld.x += xr[jj] * wd_j.x; pld.y += xr[jj] * wd_j.y;
        pld.z += xr[jj] * wd_j.z; pld.w += xr[jj] * wd_j.w;
    }
    #pragma unroll
    for (int o = 1; o < 16; o <<= 1) {
        pls.x += __shfl_xor(pls.x, o, 64); pls.y += __shfl_xor(pls.y, o, 64);
        pls.z += __shfl_xor(pls.z, o, 64); pls.w += __shfl_xor(pls.w, o, 64);
        pld.x += __shfl_xor(pld.x, o, 64); pld.y += __shfl_xor(pld.y, o, 64);
        pld.z += __shfl_xor(pld.z, o, 64); pld.w += __shfl_xor(pld.w, o, 64);
    }
    if (c4 == 0) {
        ls4[r] = pls;
        ld4[r] = pld;
    }
}

// ---------------- fused softmax + x-aggregate: y[n][h*64+c] = sum_j alpha_hj x[s_j][c] ----------------
// softmax: 16-lane groups, s_e head stride 68 (banks {0,4,8,12}) -> conflict-free.
// gather: lane = head*16+c4 reads x rows as float4 (256B/edge), 1 broadcast ds_read/edge.
__global__ __launch_bounds__(256) void k_aggx(const float4* __restrict__ x4, const float4* __restrict__ ls4,
                                              const float4* __restrict__ ld4, const int* __restrict__ rowptr_p,
                                              const int* __restrict__ csr_src, const int* __restrict__ deg,
                                              float4* __restrict__ y4) {
    __shared__ float s_e[4][4][4 * 68];   // [wave][node][head*68 + j], j < 64
    __shared__ int   s_src[4][4][64];     // [wave][node][j]
    __shared__ float s_den[4][4][4];      // [wave][node][head]
    int b = blockIdx.x;                   // 0..3999
    int xcd = b & 7, s = b >> 3;          // XCD round-robin
    int tid = threadIdx.x;
    int wid = tid >> 6, lane = tid & 63;
    int w = s * 4 + wid;                  // 0..1999 per XCD
    int g = xcd + 8 * (w / 250);
    int n0 = (w % 250) * 4;
    int nsub = lane >> 4;                 // node slot 0..3 (softmax phase)
    int j0 = lane & 15;                   // edge slot within group
    int n_s = n0 + nsub;
    int rs = rowptr_p[n_s];
    int dgp = rowptr_p[n_s + 1] - rs;     // multiple of 8
    int dg = deg[n_s];
    int dg16 = (dgp + 15) & ~15;
    if (dg16 > 64) dg16 = 64;             // safety clamp
    if (dgp > 64) dgp = 64;
    float4 ldv = ld4[(size_t)g * NNODE + n_s];
    const float4* lsg = ls4 + (size_t)g * NNODE;

    // --- pass A: logits + running max ---
    float4 mx = make_float4(-1e30f, -1e30f, -1e30f, -1e30f);
    for (int base = 0; base < dg16; base += 16) {
        int j = base + j0;
        int sv = n_s;
        if (j < dgp) sv = csr_src[rs + j];
        s_src[wid][nsub][j] = sv;
        float4 lo = make_float4(-1e30f, -1e30f, -1e30f, -1e30f);
        if (j < dg) {
            float4 t = lsg[sv];
            t.x += ldv.x; t.y += ldv.y; t.z += ldv.z; t.w += ldv.w;
            t.x = fmaxf(t.x, 0.2f * t.x); t.y = fmaxf(t.y, 0.2f * t.y);
            t.z = fmaxf(t.z, 0.2f * t.z); t.w = fmaxf(t.w, 0.2f * t.w);
            lo = t;
            mx.x = fmaxf(mx.x, lo.x); mx.y = fmaxf(mx.y, lo.y);
            mx.z = fmaxf(mx.z, lo.z); mx.w = fmaxf(mx.w, lo.w);
        }
        s_e[wid][nsub][0 * 68 + j] = lo.x;
        s_e[wid][nsub][1 * 68 + j] = lo.y;
        s_e[wid][nsub][2 * 68 + j] = lo.z;
        s_e[wid][nsub][3 * 68 + j] = lo.w;
    }
    #pragma unroll
    for (int o = 1; o < 16; o <<= 1) {
        mx.x = fmaxf(mx.x, __shfl_xor(mx.x, o, 64));
        mx.y = fmaxf(mx.y, __shfl_xor(mx.y, o, 64));
        mx.z = fmaxf(mx.z, __shfl_xor(mx.z, o, 64));
        mx.w = fmaxf(mx.w, __shfl_xor(mx.w, o, 64));
    }
    // --- pass B: exp + denominator; store unnormalized e (zeros for j >= dg) ---
    float4 den = make_float4(0.f, 0.f, 0.f, 0.f);
    for (int base = 0; base < dg16; base += 16) {
        int j = base + j0;
        float4 e = make_float4(0.f, 0.f, 0.f, 0.f);
        if (j < dg) {
            e.x = expf(s_e[wid][nsub][0 * 68 + j] - mx.x);
            e.y = expf(s_e[wid][nsub][1 * 68 + j] - mx.y);
            e.z = expf(s_e[wid][nsub][2 * 68 + j] - mx.z);
            e.w = expf(s_e[wid][nsub][3 * 68 + j] - mx.w);
        }
        den.x += e.x; den.y += e.y; den.z += e.z; den.w += e.w;
        s_e[wid][nsub][0 * 68 + j] = e.x;
        s_e[wid][nsub][1 * 68 + j] = e.y;
        s_e[wid][nsub][2 * 68 + j] = e.z;
        s_e[wid][nsub][3 * 68 + j] = e.w;
    }
    #pragma unroll
    for (int o = 1; o < 16; o <<= 1) {
        den.x += __shfl_xor(den.x, o, 64);
        den.y += __shfl_xor(den.y, o, 64);
        den.z += __shfl_xor(den.z, o, 64);
        den.w += __shfl_xor(den.w, o, 64);
    }
    if (j0 == 0) {
        s_den[wid][nsub][0] = den.x;
        s_den[wid][nsub][1] = den.y;
        s_den[wid][nsub][2] = den.z;
        s_den[wid][nsub][3] = den.w;
    }

    // --- gather phase: lane = head*16 + c4; x-row gathers, all nodes before epilogue ---
    int head = lane >> 4, c4 = lane & 15;
    const float4* xg = x4 + (size_t)g * NNODE * 16 + c4;
    float4 acc[4];
    #pragma unroll
    for (int nn = 0; nn < 4; nn++) acc[nn] = make_float4(0.f, 0.f, 0.f, 0.f);
    #pragma unroll
    for (int nn = 0; nn < 4; nn++) {
        int dgc = __shfl(dgp, nn * 16, 64);
        const float* ep = &s_e[wid][nn][head * 68];
        const int* sp = &s_src[wid][nn][0];
        for (int q = 0; q < dgc; q += 8) {
            int sj[8]; float av[8];
            #pragma unroll
            for (int u = 0; u < 8; u++) {
                sj[u] = sp[q + u];
                av[u] = ep[q + u];
            }
            float4 xv[8];
            #pragma unroll
            for (int u = 0; u < 8; u++) xv[u] = xg[(size_t)sj[u] * 16];
            #pragma unroll
            for (int u = 0; u < 8; u++) {
                acc[nn].x += av[u] * xv[u].x;
                acc[nn].y += av[u] * xv[u].y;
                acc[nn].z += av[u] * xv[u].z;
                acc[nn].w += av[u] * xv[u].w;
            }
        }
    }
    #pragma unroll
    for (int nn = 0; nn < 4; nn++) {
        float inv = 1.f / (s_den[wid][nn][head] + 1e-16f);
        float4 a = acc[nn];
        a.x *= inv; a.y *= inv; a.z *= inv; a.w *= inv;
        y4[((size_t)g * NNODE + n0 + nn) * 64 + lane] = a;   // y[n][h*64+c] as float4
    }
}

// ---------------- y @ W' + bias + ELU -> x_next; fused next-layer ls/ld ----------------
// y: [row][kk], kk = h*64+c. out[row][jo] = 0.25 * sum_kk y[kk] * W[c(kk)*256 + h(kk)*64 + jo] + b[jo]
__global__ __launch_bounds__(256) void k_ygemm(const float4* __restrict__ y4, const float* __restrict__ W,
                                               const float* __restrict__ bg, float* __restrict__ xout,
                                               const float4* __restrict__ wa4, const float4* __restrict__ wd4,
                                               float4* __restrict__ ls4, float4* __restrict__ ld4) {
    __shared__ float ys[32 * 132];    // [kkq][row], pitch 132
    int tid = threadIdx.x;
    int r0 = blockIdx.x * 128;
    int rg = tid >> 3;                // 0..31, 4 rows each
    int cg = tid & 7;                 // 0..7, 8 jo each
    float acc[4][8];
    #pragma unroll
    for (int i = 0; i < 4; i++)
        #pragma unroll
        for (int j = 0; j < 8; j++) acc[i][j] = 0.f;

    int srow = tid & 127;
    int sq = tid >> 7;                // 0..1
    for (int ck = 0; ck < 8; ck++) {
        __syncthreads();
        #pragma unroll
        for (int it = 0; it < 4; it++) {
            int c4i = sq + 2 * it;    // 0..7
            float4 v = y4[(size_t)(r0 + srow) * 64 + ck * 8 + c4i];
            int kq = c4i * 4;
            ys[(kq + 0) * 132 + srow] = v.x;
            ys[(kq + 1) * 132 + srow] = v.y;
            ys[(kq + 2) * 132 + srow] = v.z;
            ys[(kq + 3) * 132 + srow] = v.w;
        }
        __syncthreads();
        int kb = ck * 32;
        for (int kkq = 0; kkq < 32; kkq++) {
            int kk = kb + kkq;
            int hd = kk >> 6, c = kk & 63;
            const float* wp = W + (size_t)c * HCOL + hd * 64 + cg * 8;
            float4 w0 = *reinterpret_cast<const float4*>(&wp[0]);
            float4 w1 = *reinterpret_cast<const float4*>(&wp[4]);
            float4 yv = *reinterpret_cast<const float4*>(&ys[kkq * 132 + rg * 4]);
            float yr[4] = {yv.x, yv.y, yv.z, yv.w};
            #pragma unroll
            for (int i = 0; i < 4; i++) {
                acc[i][0] += yr[i] * w0.x; acc[i][1] += yr[i] * w0.y;
                acc[i][2] += yr[i] * w0.z; acc[i][3] += yr[i] * w0.w;
                acc[i][4] += yr[i] * w1.x; acc[i][5] += yr[i] * w1.y;
                acc[i][6] += yr[i] * w1.z; acc[i][7] += yr[i] * w1.w;
            }
        }
    }
    float4 b0 = *reinterpret_cast<const float4*>(&bg[cg * 8]);
    float4 b1 = *reinterpret_cast<const float4*>(&bg[cg * 8 + 4]);
    float bb[8] = {b0.x, b0.y, b0.z, b0.w, b1.x, b1.y, b1.z, b1.w};
    #pragma unroll
    for (int i = 0; i < 4; i++) {
        int row = r0 + rg * 4 + i;
        float r[8];
        #pragma unroll
        for (int j = 0; j < 8; j++) {
            float v = acc[i][j] * 0.25f + bb[j];
            r[j] = v > 0.f ? v : expm1f(v);
        }
        *reinterpret_cast<float4*>(&xout[(size_t)row * HID + cg * 8]) =
            make_float4(r[0], r[1], r[2], r[3]);
        *reinterpret_cast<float4*>(&xout[(size_t)row * HID + cg * 8 + 4]) =
            make_float4(r[4], r[5], r[6], r[7]);
        if (wa4) {
            float4 pls = make_float4(0.f, 0.f, 0.f, 0.f);
            float4 pld = make_float4(0.f, 0.f, 0.f, 0.f);
            #pragma unroll
            for (int jj = 0; jj < 8; jj++) {
                float4 wa_j = wa4[cg * 8 + jj];
                float4 wd_j = wd4[cg * 8 + jj];
                pls.x += r[jj] * wa_j.x; pls.y += r[jj] * wa_j.y;
                pls.z += r[jj] * wa_j.z; pls.w += r[jj] * wa_j.w;
                pld.x += r[jj] * wd_j.x; pld.y += r[jj] * wd_j.y;
                pld.z += r[jj] * wd_j.z; pld.w += r[jj] * wd_j.w;
            }
            #pragma unroll
            for (int o = 1; o < 8; o <<= 1) {
                pls.x += __shfl_xor(pls.x, o, 64); pls.y += __shfl_xor(pls.y, o, 64);
                pls.z += __shfl_xor(pls.z, o, 64); pls.w += __shfl_xor(pls.w, o, 64);
                pld.x += __shfl_xor(pld.x, o, 64); pld.y += __shfl_xor(pld.y, o, 64);
                pld.z += __shfl_xor(pld.z, o, 64); pld.w += __shfl_xor(pld.w, o, 64);
            }
            if (cg == 0) {
                ls4[row] = pls;
                ld4[row] = pld;
            }
        }
    }
}

// ---------------- GRU input GEMM: 500 K-slices, full 64x192 tile/block, no atomics ----------------
__global__ __launch_bounds__(256) void k_gi_gemm(const float* __restrict__ x, const float* __restrict__ W_ih,
                                                 float* __restrict__ gip) {
    __shared__ float xs[32 * 68];    // [kk][row], pitch 68
    __shared__ float ws[32 * 196];   // [kk][col 0..191], pitch 196
    int k0 = blockIdx.x * GIK;
    int tid = threadIdx.x;
    int lane = tid & 63;
    int wv = tid >> 6;
    int tx = tid & 15, ty = tid >> 4;
    float4 accs[4][3];
    #pragma unroll
    for (int i = 0; i < 4; i++)
        #pragma unroll
        for (int j = 0; j < 3; j++) accs[i][j] = make_float4(0.f, 0.f, 0.f, 0.f);

    for (int kt = 0; kt < GIK / 32; kt++) {
        int kb = k0 + kt * 32;
        #pragma unroll
        for (int it = 0; it < 2; it++) {
            int kq = wv + 4 * it;
            float4 v = *reinterpret_cast<const float4*>(&x[(size_t)lane * KGI + kb + kq * 4]);
            int k = kq * 4;
            xs[(k + 0) * 68 + lane] = v.x;
            xs[(k + 1) * 68 + lane] = v.y;
            xs[(k + 2) * 68 + lane] = v.z;
            xs[(k + 3) * 68 + lane] = v.w;
        }
        #pragma unroll
        for (int cg = 0; cg < 3; cg++) {
            #pragma unroll
            for (int it = 0; it < 2; it++) {
                int kq = wv + 4 * it;
                int c = cg * 64 + lane;
                float4 v = *reinterpret_cast<const float4*>(&W_ih[(size_t)c * KGI + kb + kq * 4]);
                int k = kq * 4;
                ws[(k + 0) * 196 + c] = v.x;
                ws[(k + 1) * 196 + c] = v.y;
                ws[(k + 2) * 196 + c] = v.z;
                ws[(k + 3) * 196 + c] = v.w;
            }
        }
        __syncthreads();
        for (int kk = 0; kk < 32; kk++) {
            float4 xv = *reinterpret_cast<const float4*>(&xs[kk * 68 + ty * 4]);
            float4 w0 = *reinterpret_cast<const float4*>(&ws[kk * 196 + tx * 4]);
            float4 w1 = *reinterpret_cast<const float4*>(&ws[kk * 196 + 64 + tx * 4]);
            float4 w2 = *reinterpret_cast<const float4*>(&ws[kk * 196 + 128 + tx * 4]);
            #pragma unroll
            for (int i = 0; i < 4; i++) {
                float xi = (i == 0) ? xv.x : (i == 1) ? xv.y : (i == 2) ? xv.z : xv.w;
                accs[i][0].x += xi * w0.x; accs[i][0].y += xi * w0.y; accs[i][0].z += xi * w0.z; accs[i][0].w += xi * w0.w;
                accs[i][1].x += xi * w1.x; accs[i][1].y += xi * w1.y; accs[i][1].z += xi * w1.z; accs[i][1].w += xi * w1.w;
                accs[i][2].x += xi * w2.x; accs[i][2].y += xi * w2.y; accs[i][2].z += xi * w2.z; accs[i][2].w += xi * w2.w;
            }
        }
        __syncthreads();
    }
    float* out = gip + (size_t)blockIdx.x * GOSZ;
    #pragma unroll
    for (int i = 0; i < 4; i++)
        #pragma unroll
        for (int j = 0; j < 3; j++)
            *reinterpret_cast<float4*>(&out[(ty * 4 + i) * GOUT + j * 64 + tx * 4]) = accs[i][j];
}

__global__ void k_gi_reduce1(const float* __restrict__ gip, float* __restrict__ gip2) {
    int idx = blockIdx.x * 256 + threadIdx.x;     // 0..GOSZ-1
    const float* p = gip + (size_t)blockIdx.y * 50 * GOSZ + idx;
    float a = 0.f;
    #pragma unroll 5
    for (int s = 0; s < 50; s++) a += p[(size_t)s * GOSZ];
    gip2[blockIdx.y * GOSZ + idx] = a;
}

__global__ void k_gi_reduce2(const float* __restrict__ gip2, const float* __restrict__ b_ih,
                             float* __restrict__ gi) {
    int idx = blockIdx.x * 256 + threadIdx.x;
    float a = b_ih[idx % GOUT];
    #pragma unroll
    for (int y = 0; y < 10; y++) a += gip2[(size_t)y * GOSZ + idx];
    gi[idx] = a;
}

// ---------------- GRU scan (single block) ----------------
__global__ __launch_bounds__(256) void k_gru(const float* __restrict__ gi, const float* __restrict__ W_hh,
                                             const float* __restrict__ b_hh, float* __restrict__ hT) {
    __shared__ float Wt[64 * 192];   // [c][j] transposed
    __shared__ float hs[4][64];
    __shared__ float gh[4][192];
    int tid = threadIdx.x;
    for (int idx = tid; idx < 192 * 64; idx += 256) {
        int j = idx >> 6, c = idx & 63;
        Wt[c * 192 + j] = W_hh[idx];
    }
    int b_ = tid >> 6, c_ = tid & 63;
    hs[b_][c_] = 0.f;
    __syncthreads();
    for (int t = 0; t < TT; t++) {
        #pragma unroll
        for (int q = 0; q < 3; q++) {
            int p = tid + 256 * q;
            int bb = p / GOUT, j = p % GOUT;
            float a = b_hh[j];
            for (int c = 0; c < 64; c++) a += hs[bb][c] * Wt[c * 192 + j];
            gh[bb][j] = a;
        }
        __syncthreads();
        int row = (b_ * TT + t) * GOUT;
        float ir = gi[row + c_], iz = gi[row + 64 + c_], in_ = gi[row + 128 + c_];
        float r = 1.f / (1.f + expf(-(ir + gh[b_][c_])));
        float z = 1.f / (1.f + expf(-(iz + gh[b_][64 + c_])));
        float nv = tanhf(in_ + r * gh[b_][128 + c_]);
        float hn = (1.f - z) * nv + z * hs[b_][c_];
        hs[b_][c_] = hn;
        __syncthreads();
    }
    hT[tid] = hs[b_][c_];
}

// ---------------- final FC ----------------
__global__ void k_final(const float* __restrict__ hT, const float* __restrict__ W_fc,
                        const float* __restrict__ b_fc, float* __restrict__ out) {
    int idx = blockIdx.x * 256 + threadIdx.x;
    if (idx >= NB * NNODE) return;
    int b = idx / NNODE, n = idx % NNODE;
    float acc = b_fc[n];
    #pragma unroll
    for (int c = 0; c < HID; c++) acc += hT[b * HID + c] * W_fc[c * NNODE + n];
    out[idx] = acc;
}

extern "C" void kernel_launch(void* const* d_in, const int* in_sizes, int n_in,
                              void* d_out, int out_size, void* d_ws, size_t ws_size,
                              hipStream_t stream) {
    const float* x_seq  = (const float*)d_in[0];
    const int*   eidx   = (const int*)  d_in[1];
    // d_in[2] edge_weight: unused by GATConv
    const float* W_in   = (const float*)d_in[3];
    const float* b_in   = (const float*)d_in[4];
    const float* Wg     = (const float*)d_in[5];
    const float* a_src  = (const float*)d_in[6];
    const float* a_dst  = (const float*)d_in[7];
    const float* bg     = (const float*)d_in[8];
    const float* W_ih   = (const float*)d_in[9];
    const float* W_hh   = (const float*)d_in[10];
    const float* b_ih   = (const float*)d_in[11];
    const float* b_hh   = (const float*)d_in[12];
    const float* W_fc   = (const float*)d_in[13];
    const float* b_fc   = (const float*)d_in[14];
    float* out = (float*)d_out;

    float* wsf = (float*)d_ws;
    size_t off = 0;
    float* x0     = wsf + off; off += (size_t)ROWS * HID;       // 4,096,000
    float* ybuf   = wsf + off; off += (size_t)ROWS * HCOL;      // 16,384,000
    float* lsb    = wsf + off; off += (size_t)ROWS * HEADS;     // 256,000
    float* ldb    = wsf + off; off += (size_t)ROWS * HEADS;     // 256,000
    float* wab    = wsf + off; off += NL * HCOL;                // 1,280
    float* wdb    = wsf + off; off += NL * HCOL;                // 1,280
    float* gib    = wsf + off; off += GOSZ;                     // 12,288
    float* hTb    = wsf + off; off += 256;
    int* ib = (int*)(wsf + off);
    int* src_e    = ib;          ib += EP;
    int* dst_e    = ib;          ib += EP;
    int* rowptr_p = ib;          ib += NNODE + 1;
    int* csr_src  = ib;          ib += EPAD;
    int* deg      = ib;          ib += NNODE;
    int* fill     = ib;          ib += NNODE;

    // gi partials alias ybuf (dead after last k_ygemm): (500+10)*12288 floats << 16.38M
    float* gip  = ybuf;
    float* gip2 = ybuf + (size_t)KSPLIT * GOSZ;

    k_build_edges<<<(EP + 255) / 256, 256, 0, stream>>>(eidx, src_e, dst_e, deg, fill);
    k_csr_count<<<(EP + 255) / 256, 256, 0, stream>>>(dst_e, deg);
    k_csr_scan<<<1, 256, 0, stream>>>(deg, rowptr_p);
    k_csr_fill<<<(EP + 255) / 256, 256, 0, stream>>>(src_e, dst_e, rowptr_p, fill, csr_src);
    k_pad_fill<<<(NNODE + 255) / 256, 256, 0, stream>>>(rowptr_p, deg, csr_src);

    k_wa<<<10, 256, 0, stream>>>(Wg, a_src, a_dst, wab, wdb);

    k_input_fc<<<ROWS * 16 / 256, 256, 0, stream>>>(
        x_seq, (const float4*)W_in, (const float4*)b_in,
        (const float4*)wab, (const float4*)wdb, (float4*)x0, (float4*)lsb, (float4*)ldb);

    for (int l = 0; l < NL; l++) {
        k_aggx<<<ROWS / 16, 256, 0, stream>>>(
            (const float4*)x0, (const float4*)lsb, (const float4*)ldb, rowptr_p, csr_src, deg,
            (float4*)ybuf);
        const float4* wa_next = (l + 1 < NL) ? (const float4*)(wab + (size_t)(l + 1) * HCOL) : nullptr;
        const float4* wd_next = (l + 1 < NL) ? (const float4*)(wdb + (size_t)(l + 1) * HCOL) : nullptr;
        k_ygemm<<<ROWS / 128, 256, 0, stream>>>(
            (const float4*)ybuf, Wg + (size_t)l * HID * HCOL, bg + (size_t)l * HID, x0,
            wa_next, wd_next, (float4*)lsb, (float4*)ldb);
    }

    k_gi_gemm<<<KSPLIT, 256, 0, stream>>>(x0, W_ih, gip);
    k_gi_reduce1<<<dim3(GOSZ / 256, 10), 256, 0, stream>>>(gip, gip2);
    k_gi_reduce2<<<GOSZ / 256, 256, 0, stream>>>(gip2, b_ih, gib);
    k_gru<<<1, 256, 0, stream>>>(gib, W_hh, b_hh, hTb);
    k_final<<<(NB * NNODE + 255) / 256, 256, 0, stream>>>(hTb, W_fc, b_fc, out);
}

// Round 14
// 652.525 us; speedup vs baseline: 1.0349x; 1.0349x over previous
//
#include <hip/hip_runtime.h>
#include <math.h>

#define NB 4
#define TT 16
#define NNODE 1000
#define FIN 8
#define EE 8000
#define EP 9000          // E + N self loops
#define EPAD 16384       // max padded edges (pad rows to mult of 8)
#define HID 64
#define HEADS 4
#define NL 5
#define GG (NB*TT)       // 64 graphs
#define ROWS (GG*NNODE)  // 64000
#define HCOL (HEADS*HID) // 256
#define KGI (NNODE*HID)  // 64000
#define GOUT 192         // 3*HID
#define GIK 128          // K-slice per gi-gemm block
#define KSPLIT (KGI/GIK) // 500 partial slabs
#define GOSZ (GG*GOUT)   // 12288

// ---------------- edge prep ----------------
__global__ void k_build_edges(const int* __restrict__ eidx, int* __restrict__ src_e,
                              int* __restrict__ dst_e, int* __restrict__ deg, int* __restrict__ fill) {
    int i = blockIdx.x * blockDim.x + threadIdx.x;
    if (i < EP) {
        int s, d;
        if (i < EE) { s = eidx[i]; d = eidx[EE + i]; }
        else { s = i - EE; d = i - EE; }
        src_e[i] = s; dst_e[i] = d;
    }
    if (i < NNODE) { deg[i] = 0; fill[i] = 0; }
}

__global__ void k_csr_count(const int* __restrict__ dst_e, int* __restrict__ deg) {
    int i = blockIdx.x * blockDim.x + threadIdx.x;
    if (i < EP) atomicAdd(&deg[dst_e[i]], 1);
}

// parallel inclusive scan of PADDED degrees (pad to multiple of 8)
__global__ __launch_bounds__(256) void k_csr_scan(const int* __restrict__ deg, int* __restrict__ rowptr_p) {
    __shared__ int s[1024];
    int tid = threadIdx.x;
    for (int i = tid; i < 1024; i += 256) s[i] = (i < NNODE) ? ((deg[i] + 7) & ~7) : 0;
    __syncthreads();
    for (int off = 1; off < 1024; off <<= 1) {
        int t[4];
        #pragma unroll
        for (int q = 0; q < 4; q++) { int i = tid + 256 * q; t[q] = (i >= off) ? s[i - off] : 0; }
        __syncthreads();
        #pragma unroll
        for (int q = 0; q < 4; q++) { int i = tid + 256 * q; s[i] += t[q]; }
        __syncthreads();
    }
    for (int i = tid; i < NNODE; i += 256) rowptr_p[i + 1] = s[i];
    if (tid == 0) rowptr_p[0] = 0;
}

__global__ void k_csr_fill(const int* __restrict__ src_e, const int* __restrict__ dst_e,
                           const int* __restrict__ rowptr_p, int* __restrict__ fill,
                           int* __restrict__ csr_src) {
    int i = blockIdx.x * blockDim.x + threadIdx.x;
    if (i < EP) {
        int d = dst_e[i];
        int pos = atomicAdd(&fill[d], 1);
        csr_src[rowptr_p[d] + pos] = src_e[i];
    }
}

// fill pad slots with dummy self-edges (they get alpha = 0 in the fused agg)
__global__ void k_pad_fill(const int* __restrict__ rowptr_p, const int* __restrict__ deg,
                           int* __restrict__ csr_src) {
    int n = blockIdx.x * blockDim.x + threadIdx.x;
    if (n >= NNODE) return;
    int rs = rowptr_p[n], re = rowptr_p[n + 1];
    for (int j = rs + deg[n]; j < re; j++) csr_src[j] = n;
}

// ---------------- precompute wa/wd: wa[l][j][h] = sum_c W_l[j, h*64+c] * a_src[l,h,c] ----------------
__global__ void k_wa(const float* __restrict__ Wg, const float* __restrict__ a_src,
                     const float* __restrict__ a_dst, float* __restrict__ wa, float* __restrict__ wd) {
    int t = blockIdx.x * 256 + threadIdx.x;      // 2*NL*HID*HEADS = 2560
    if (t >= 2 * NL * HID * HEADS) return;
    int kind = t >= NL * HID * HEADS;
    int u = t - kind * NL * HID * HEADS;
    int l = u >> 8;
    int rem = u & 255;
    int j = rem >> 2, hd = rem & 3;
    const float* a = (kind ? a_dst : a_src) + (size_t)l * HCOL + hd * HID;
    const float* Wl = Wg + (size_t)l * HID * HCOL + (size_t)j * HCOL + hd * HID;
    float acc = 0.f;
    #pragma unroll 8
    for (int c = 0; c < HID; c++) acc += Wl[c] * a[c];
    float* out = kind ? wd : wa;
    out[(size_t)l * HCOL + j * 4 + hd] = acc;
}

// ---------------- input projection + fused layer-0 ls/ld ----------------
__global__ void k_input_fc(const float* __restrict__ xseq, const float4* __restrict__ Win4,
                           const float4* __restrict__ b_in4, const float4* __restrict__ wa04,
                           const float4* __restrict__ wd04, float4* __restrict__ x0,
                           float4* __restrict__ ls4, float4* __restrict__ ld4) {
    int idx = blockIdx.x * 256 + threadIdx.x;   // ROWS*16 threads
    int r = idx >> 4, c4 = idx & 15;
    float4 acc = b_in4[c4];
    #pragma unroll
    for (int k = 0; k < FIN; k++) {
        float xv = xseq[r * FIN + k];
        float4 w = Win4[k * 16 + c4];
        acc.x += xv * w.x; acc.y += xv * w.y; acc.z += xv * w.z; acc.w += xv * w.w;
    }
    x0[idx] = acc;
    float xr[4] = {acc.x, acc.y, acc.z, acc.w};
    float4 pls = make_float4(0.f, 0.f, 0.f, 0.f);
    float4 pld = make_float4(0.f, 0.f, 0.f, 0.f);
    #pragma unroll
    for (int jj = 0; jj < 4; jj++) {
        float4 wa_j = wa04[c4 * 4 + jj];
        float4 wd_j = wd04[c4 * 4 + jj];
        pls.x += xr[jj] * wa_j.x; pls.y += xr[jj] * wa_j.y;
        pls.z += xr[jj] * wa_j.z; pls.w += xr[jj] * wa_j.w;
        pld.x += xr[jj] * wd_j.x; pld.y += xr[jj] * wd_j.y;
        pld.z += xr[jj] * wd_j.z; pld.w += xr[jj] * wd_j.w;
    }
    #pragma unroll
    for (int o = 1; o < 16; o <<= 1) {
        pls.x += __shfl_xor(pls.x, o, 64); pls.y += __shfl_xor(pls.y, o, 64);
        pls.z += __shfl_xor(pls.z, o, 64); pls.w += __shfl_xor(pls.w, o, 64);
        pld.x += __shfl_xor(pld.x, o, 64); pld.y += __shfl_xor(pld.y, o, 64);
        pld.z += __shfl_xor(pld.z, o, 64); pld.w += __shfl_xor(pld.w, o, 64);
    }
    if (c4 == 0) {
        ls4[r] = pls;
        ld4[r] = pld;
    }
}

// ---------------- fused softmax + x-aggregate: y[n][h*64+c] = sum_j alpha_hj x[s_j][c] ----------------
__global__ __launch_bounds__(256) void k_aggx(const float4* __restrict__ x4, const float4* __restrict__ ls4,
                                              const float4* __restrict__ ld4, const int* __restrict__ rowptr_p,
                                              const int* __restrict__ csr_src, const int* __restrict__ deg,
                                              float4* __restrict__ y4) {
    __shared__ float s_e[4][4][4 * 68];   // [wave][node][head*68 + j], j < 64
    __shared__ int   s_src[4][4][64];     // [wave][node][j]
    __shared__ float s_den[4][4][4];      // [wave][node][head]
    int b = blockIdx.x;                   // 0..3999
    int xcd = b & 7, s = b >> 3;          // XCD round-robin
    int tid = threadIdx.x;
    int wid = tid >> 6, lane = tid & 63;
    int w = s * 4 + wid;                  // 0..1999 per XCD
    int g = xcd + 8 * (w / 250);
    int n0 = (w % 250) * 4;
    int nsub = lane >> 4;                 // node slot 0..3 (softmax phase)
    int j0 = lane & 15;                   // edge slot within group
    int n_s = n0 + nsub;
    int rs = rowptr_p[n_s];
    int dgp = rowptr_p[n_s + 1] - rs;     // multiple of 8
    int dg = deg[n_s];
    int dg16 = (dgp + 15) & ~15;
    if (dg16 > 64) dg16 = 64;             // safety clamp
    if (dgp > 64) dgp = 64;
    float4 ldv = ld4[(size_t)g * NNODE + n_s];
    const float4* lsg = ls4 + (size_t)g * NNODE;

    // --- pass A: logits + running max ---
    float4 mx = make_float4(-1e30f, -1e30f, -1e30f, -1e30f);
    for (int base = 0; base < dg16; base += 16) {
        int j = base + j0;
        int sv = n_s;
        if (j < dgp) sv = csr_src[rs + j];
        s_src[wid][nsub][j] = sv;
        float4 lo = make_float4(-1e30f, -1e30f, -1e30f, -1e30f);
        if (j < dg) {
            float4 t = lsg[sv];
            t.x += ldv.x; t.y += ldv.y; t.z += ldv.z; t.w += ldv.w;
            t.x = fmaxf(t.x, 0.2f * t.x); t.y = fmaxf(t.y, 0.2f * t.y);
            t.z = fmaxf(t.z, 0.2f * t.z); t.w = fmaxf(t.w, 0.2f * t.w);
            lo = t;
            mx.x = fmaxf(mx.x, lo.x); mx.y = fmaxf(mx.y, lo.y);
            mx.z = fmaxf(mx.z, lo.z); mx.w = fmaxf(mx.w, lo.w);
        }
        s_e[wid][nsub][0 * 68 + j] = lo.x;
        s_e[wid][nsub][1 * 68 + j] = lo.y;
        s_e[wid][nsub][2 * 68 + j] = lo.z;
        s_e[wid][nsub][3 * 68 + j] = lo.w;
    }
    #pragma unroll
    for (int o = 1; o < 16; o <<= 1) {
        mx.x = fmaxf(mx.x, __shfl_xor(mx.x, o, 64));
        mx.y = fmaxf(mx.y, __shfl_xor(mx.y, o, 64));
        mx.z = fmaxf(mx.z, __shfl_xor(mx.z, o, 64));
        mx.w = fmaxf(mx.w, __shfl_xor(mx.w, o, 64));
    }
    // --- pass B: exp + denominator; store unnormalized e (zeros for j >= dg) ---
    float4 den = make_float4(0.f, 0.f, 0.f, 0.f);
    for (int base = 0; base < dg16; base += 16) {
        int j = base + j0;
        float4 e = make_float4(0.f, 0.f, 0.f, 0.f);
        if (j < dg) {
            e.x = expf(s_e[wid][nsub][0 * 68 + j] - mx.x);
            e.y = expf(s_e[wid][nsub][1 * 68 + j] - mx.y);
            e.z = expf(s_e[wid][nsub][2 * 68 + j] - mx.z);
            e.w = expf(s_e[wid][nsub][3 * 68 + j] - mx.w);
        }
        den.x += e.x; den.y += e.y; den.z += e.z; den.w += e.w;
        s_e[wid][nsub][0 * 68 + j] = e.x;
        s_e[wid][nsub][1 * 68 + j] = e.y;
        s_e[wid][nsub][2 * 68 + j] = e.z;
        s_e[wid][nsub][3 * 68 + j] = e.w;
    }
    #pragma unroll
    for (int o = 1; o < 16; o <<= 1) {
        den.x += __shfl_xor(den.x, o, 64);
        den.y += __shfl_xor(den.y, o, 64);
        den.z += __shfl_xor(den.z, o, 64);
        den.w += __shfl_xor(den.w, o, 64);
    }
    if (j0 == 0) {
        s_den[wid][nsub][0] = den.x;
        s_den[wid][nsub][1] = den.y;
        s_den[wid][nsub][2] = den.z;
        s_den[wid][nsub][3] = den.w;
    }

    // --- gather phase: lane = head*16 + c4; x-row gathers, all nodes before epilogue ---
    int head = lane >> 4, c4 = lane & 15;
    const float4* xg = x4 + (size_t)g * NNODE * 16 + c4;
    float4 acc[4];
    #pragma unroll
    for (int nn = 0; nn < 4; nn++) acc[nn] = make_float4(0.f, 0.f, 0.f, 0.f);
    #pragma unroll
    for (int nn = 0; nn < 4; nn++) {
        int dgc = __shfl(dgp, nn * 16, 64);
        const float* ep = &s_e[wid][nn][head * 68];
        const int* sp = &s_src[wid][nn][0];
        for (int q = 0; q < dgc; q += 8) {
            int sj[8]; float av[8];
            #pragma unroll
            for (int u = 0; u < 8; u++) {
                sj[u] = sp[q + u];
                av[u] = ep[q + u];
            }
            float4 xv[8];
            #pragma unroll
            for (int u = 0; u < 8; u++) xv[u] = xg[(size_t)sj[u] * 16];
            #pragma unroll
            for (int u = 0; u < 8; u++) {
                acc[nn].x += av[u] * xv[u].x;
                acc[nn].y += av[u] * xv[u].y;
                acc[nn].z += av[u] * xv[u].z;
                acc[nn].w += av[u] * xv[u].w;
            }
        }
    }
    #pragma unroll
    for (int nn = 0; nn < 4; nn++) {
        float inv = 1.f / (s_den[wid][nn][head] + 1e-16f);
        float4 a = acc[nn];
        a.x *= inv; a.y *= inv; a.z *= inv; a.w *= inv;
        y4[((size_t)g * NNODE + n0 + nn) * 64 + lane] = a;   // y[n][h*64+c] as float4
    }
}

// ---------------- y @ W' K-split GEMM: grid (500, 2), 128 thr, 128x64 tile, 8x8/thread ----------------
// K-half by covers kk in [by*128, by*128+128) i.e. heads {2by, 2by+1}. Partial by=0 -> p0, by=1 -> p1.
__global__ __launch_bounds__(128) void k_ygemm2(const float4* __restrict__ y4, const float* __restrict__ W,
                                                float* __restrict__ p0, float* __restrict__ p1) {
    __shared__ float ys[64 * 132];    // [kk_local][row], pitch 132
    int tid = threadIdx.x;            // 0..127
    int r0 = blockIdx.x * 128;
    int by = blockIdx.y;              // 0..1
    int rg = tid >> 3;                // 0..15 -> rows rg*8..+7
    int cg = tid & 7;                 // 0..7  -> cols cg*8..+7
    float acc[8][8];
    #pragma unroll
    for (int i = 0; i < 8; i++)
        #pragma unroll
        for (int j = 0; j < 8; j++) acc[i][j] = 0.f;

    for (int ck = 0; ck < 2; ck++) {
        __syncthreads();
        // stage 64 kk x 128 rows (transposed); row = tid -> wave-consecutive, conflict-free
        #pragma unroll
        for (int it = 0; it < 16; it++) {
            float4 v = y4[(size_t)(r0 + tid) * 64 + by * 32 + ck * 16 + it];
            int kq = it * 4;
            ys[(kq + 0) * 132 + tid] = v.x;
            ys[(kq + 1) * 132 + tid] = v.y;
            ys[(kq + 2) * 132 + tid] = v.z;
            ys[(kq + 3) * 132 + tid] = v.w;
        }
        __syncthreads();
        int hd = by * 2 + ck;                       // head for this 64-kk sub-chunk
        const float* wp = W + (size_t)hd * 64 + cg * 8;
        for (int kk = 0; kk < 64; kk++) {
            float4 w0 = *reinterpret_cast<const float4*>(&wp[(size_t)kk * HCOL]);
            float4 w1 = *reinterpret_cast<const float4*>(&wp[(size_t)kk * HCOL + 4]);
            float4 xv0 = *reinterpret_cast<const float4*>(&ys[kk * 132 + rg * 8]);
            float4 xv1 = *reinterpret_cast<const float4*>(&ys[kk * 132 + rg * 8 + 4]);
            float xr[8] = {xv0.x, xv0.y, xv0.z, xv0.w, xv1.x, xv1.y, xv1.z, xv1.w};
            #pragma unroll
            for (int i = 0; i < 8; i++) {
                acc[i][0] += xr[i] * w0.x; acc[i][1] += xr[i] * w0.y;
                acc[i][2] += xr[i] * w0.z; acc[i][3] += xr[i] * w0.w;
                acc[i][4] += xr[i] * w1.x; acc[i][5] += xr[i] * w1.y;
                acc[i][6] += xr[i] * w1.z; acc[i][7] += xr[i] * w1.w;
            }
        }
    }
    float* pb = by ? p1 : p0;
    #pragma unroll
    for (int i = 0; i < 8; i++) {
        int row = r0 + rg * 8 + i;
        *reinterpret_cast<float4*>(&pb[(size_t)row * 64 + cg * 8]) =
            make_float4(acc[i][0], acc[i][1], acc[i][2], acc[i][3]);
        *reinterpret_cast<float4*>(&pb[(size_t)row * 64 + cg * 8 + 4]) =
            make_float4(acc[i][4], acc[i][5], acc[i][6], acc[i][7]);
    }
}

// ---------------- combine partials + bias + ELU -> x0; fused next-layer ls/ld ----------------
__global__ void k_ycomb(const float* __restrict__ p0, const float* __restrict__ p1,
                        const float* __restrict__ bg, const float4* __restrict__ wa4,
                        const float4* __restrict__ wd4, float* __restrict__ xout,
                        float4* __restrict__ ls4, float4* __restrict__ ld4) {
    int idx = blockIdx.x * 256 + threadIdx.x;   // ROWS*16
    int r = idx >> 4, c4 = idx & 15;
    float4 a = *reinterpret_cast<const float4*>(&p0[(size_t)r * 64 + c4 * 4]);
    float4 b = *reinterpret_cast<const float4*>(&p1[(size_t)r * 64 + c4 * 4]);
    float4 bb = *reinterpret_cast<const float4*>(&bg[c4 * 4]);
    float rr[4];
    rr[0] = (a.x + b.x) * 0.25f + bb.x;
    rr[1] = (a.y + b.y) * 0.25f + bb.y;
    rr[2] = (a.z + b.z) * 0.25f + bb.z;
    rr[3] = (a.w + b.w) * 0.25f + bb.w;
    #pragma unroll
    for (int j = 0; j < 4; j++) rr[j] = rr[j] > 0.f ? rr[j] : expm1f(rr[j]);
    *reinterpret_cast<float4*>(&xout[(size_t)r * 64 + c4 * 4]) =
        make_float4(rr[0], rr[1], rr[2], rr[3]);
    if (wa4) {
        float4 pls = make_float4(0.f, 0.f, 0.f, 0.f);
        float4 pld = make_float4(0.f, 0.f, 0.f, 0.f);
        #pragma unroll
        for (int jj = 0; jj < 4; jj++) {
            float4 wa_j = wa4[c4 * 4 + jj];
            float4 wd_j = wd4[c4 * 4 + jj];
            pls.x += rr[jj] * wa_j.x; pls.y += rr[jj] * wa_j.y;
            pls.z += rr[jj] * wa_j.z; pls.w += rr[jj] * wa_j.w;
            pld.x += rr[jj] * wd_j.x; pld.y += rr[jj] * wd_j.y;
            pld.z += rr[jj] * wd_j.z; pld.w += rr[jj] * wd_j.w;
        }
        #pragma unroll
        for (int o = 1; o < 16; o <<= 1) {
            pls.x += __shfl_xor(pls.x, o, 64); pls.y += __shfl_xor(pls.y, o, 64);
            pls.z += __shfl_xor(pls.z, o, 64); pls.w += __shfl_xor(pls.w, o, 64);
            pld.x += __shfl_xor(pld.x, o, 64); pld.y += __shfl_xor(pld.y, o, 64);
            pld.z += __shfl_xor(pld.z, o, 64); pld.w += __shfl_xor(pld.w, o, 64);
        }
        if (c4 == 0) {
            ls4[r] = pls;
            ld4[r] = pld;
        }
    }
}

// ---------------- GRU input GEMM: 500 K-slices, full 64x192 tile/block, no atomics ----------------
__global__ __launch_bounds__(256) void k_gi_gemm(const float* __restrict__ x, const float* __restrict__ W_ih,
                                                 float* __restrict__ gip) {
    __shared__ float xs[32 * 68];    // [kk][row], pitch 68
    __shared__ float ws[32 * 196];   // [kk][col 0..191], pitch 196
    int k0 = blockIdx.x * GIK;
    int tid = threadIdx.x;
    int lane = tid & 63;
    int wv = tid >> 6;
    int tx = tid & 15, ty = tid >> 4;
    float4 accs[4][3];
    #pragma unroll
    for (int i = 0; i < 4; i++)
        #pragma unroll
        for (int j = 0; j < 3; j++) accs[i][j] = make_float4(0.f, 0.f, 0.f, 0.f);

    for (int kt = 0; kt < GIK / 32; kt++) {
        int kb = k0 + kt * 32;
        #pragma unroll
        for (int it = 0; it < 2; it++) {
            int kq = wv + 4 * it;
            float4 v = *reinterpret_cast<const float4*>(&x[(size_t)lane * KGI + kb + kq * 4]);
            int k = kq * 4;
            xs[(k + 0) * 68 + lane] = v.x;
            xs[(k + 1) * 68 + lane] = v.y;
            xs[(k + 2) * 68 + lane] = v.z;
            xs[(k + 3) * 68 + lane] = v.w;
        }
        #pragma unroll
        for (int cg = 0; cg < 3; cg++) {
            #pragma unroll
            for (int it = 0; it < 2; it++) {
                int kq = wv + 4 * it;
                int c = cg * 64 + lane;
                float4 v = *reinterpret_cast<const float4*>(&W_ih[(size_t)c * KGI + kb + kq * 4]);
                int k = kq * 4;
                ws[(k + 0) * 196 + c] = v.x;
                ws[(k + 1) * 196 + c] = v.y;
                ws[(k + 2) * 196 + c] = v.z;
                ws[(k + 3) * 196 + c] = v.w;
            }
        }
        __syncthreads();
        for (int kk = 0; kk < 32; kk++) {
            float4 xv = *reinterpret_cast<const float4*>(&xs[kk * 68 + ty * 4]);
            float4 w0 = *reinterpret_cast<const float4*>(&ws[kk * 196 + tx * 4]);
            float4 w1 = *reinterpret_cast<const float4*>(&ws[kk * 196 + 64 + tx * 4]);
            float4 w2 = *reinterpret_cast<const float4*>(&ws[kk * 196 + 128 + tx * 4]);
            #pragma unroll
            for (int i = 0; i < 4; i++) {
                float xi = (i == 0) ? xv.x : (i == 1) ? xv.y : (i == 2) ? xv.z : xv.w;
                accs[i][0].x += xi * w0.x; accs[i][0].y += xi * w0.y; accs[i][0].z += xi * w0.z; accs[i][0].w += xi * w0.w;
                accs[i][1].x += xi * w1.x; accs[i][1].y += xi * w1.y; accs[i][1].z += xi * w1.z; accs[i][1].w += xi * w1.w;
                accs[i][2].x += xi * w2.x; accs[i][2].y += xi * w2.y; accs[i][2].z += xi * w2.z; accs[i][2].w += xi * w2.w;
            }
        }
        __syncthreads();
    }
    float* out = gip + (size_t)blockIdx.x * GOSZ;
    #pragma unroll
    for (int i = 0; i < 4; i++)
        #pragma unroll
        for (int j = 0; j < 3; j++)
            *reinterpret_cast<float4*>(&out[(ty * 4 + i) * GOUT + j * 64 + tx * 4]) = accs[i][j];
}

__global__ void k_gi_reduce1(const float* __restrict__ gip, float* __restrict__ gip2) {
    int idx = blockIdx.x * 256 + threadIdx.x;     // 0..GOSZ-1
    const float* p = gip + (size_t)blockIdx.y * 50 * GOSZ + idx;
    float a = 0.f;
    #pragma unroll 5
    for (int s = 0; s < 50; s++) a += p[(size_t)s * GOSZ];
    gip2[blockIdx.y * GOSZ + idx] = a;
}

__global__ void k_gi_reduce2(const float* __restrict__ gip2, const float* __restrict__ b_ih,
                             float* __restrict__ gi) {
    int idx = blockIdx.x * 256 + threadIdx.x;
    float a = b_ih[idx % GOUT];
    #pragma unroll
    for (int y = 0; y < 10; y++) a += gip2[(size_t)y * GOSZ + idx];
    gi[idx] = a;
}

// ---------------- GRU scan (single block) ----------------
__global__ __launch_bounds__(256) void k_gru(const float* __restrict__ gi, const float* __restrict__ W_hh,
                                             const float* __restrict__ b_hh, float* __restrict__ hT) {
    __shared__ float Wt[64 * 192];   // [c][j] transposed
    __shared__ float hs[4][64];
    __shared__ float gh[4][192];
    int tid = threadIdx.x;
    for (int idx = tid; idx < 192 * 64; idx += 256) {
        int j = idx >> 6, c = idx & 63;
        Wt[c * 192 + j] = W_hh[idx];
    }
    int b_ = tid >> 6, c_ = tid & 63;
    hs[b_][c_] = 0.f;
    __syncthreads();
    for (int t = 0; t < TT; t++) {
        #pragma unroll
        for (int q = 0; q < 3; q++) {
            int p = tid + 256 * q;
            int bb = p / GOUT, j = p % GOUT;
            float a = b_hh[j];
            for (int c = 0; c < 64; c++) a += hs[bb][c] * Wt[c * 192 + j];
            gh[bb][j] = a;
        }
        __syncthreads();
        int row = (b_ * TT + t) * GOUT;
        float ir = gi[row + c_], iz = gi[row + 64 + c_], in_ = gi[row + 128 + c_];
        float r = 1.f / (1.f + expf(-(ir + gh[b_][c_])));
        float z = 1.f / (1.f + expf(-(iz + gh[b_][64 + c_])));
        float nv = tanhf(in_ + r * gh[b_][128 + c_]);
        float hn = (1.f - z) * nv + z * hs[b_][c_];
        hs[b_][c_] = hn;
        __syncthreads();
    }
    hT[tid] = hs[b_][c_];
}

// ---------------- final FC ----------------
__global__ void k_final(const float* __restrict__ hT, const float* __restrict__ W_fc,
                        const float* __restrict__ b_fc, float* __restrict__ out) {
    int idx = blockIdx.x * 256 + threadIdx.x;
    if (idx >= NB * NNODE) return;
    int b = idx / NNODE, n = idx % NNODE;
    float acc = b_fc[n];
    #pragma unroll
    for (int c = 0; c < HID; c++) acc += hT[b * HID + c] * W_fc[c * NNODE + n];
    out[idx] = acc;
}

extern "C" void kernel_launch(void* const* d_in, const int* in_sizes, int n_in,
                              void* d_out, int out_size, void* d_ws, size_t ws_size,
                              hipStream_t stream) {
    const float* x_seq  = (const float*)d_in[0];
    const int*   eidx   = (const int*)  d_in[1];
    // d_in[2] edge_weight: unused by GATConv
    const float* W_in   = (const float*)d_in[3];
    const float* b_in   = (const float*)d_in[4];
    const float* Wg     = (const float*)d_in[5];
    const float* a_src  = (const float*)d_in[6];
    const float* a_dst  = (const float*)d_in[7];
    const float* bg     = (const float*)d_in[8];
    const float* W_ih   = (const float*)d_in[9];
    const float* W_hh   = (const float*)d_in[10];
    const float* b_ih   = (const float*)d_in[11];
    const float* b_hh   = (const float*)d_in[12];
    const float* W_fc   = (const float*)d_in[13];
    const float* b_fc   = (const float*)d_in[14];
    float* out = (float*)d_out;

    float* wsf = (float*)d_ws;
    size_t off = 0;
    float* x0     = wsf + off; off += (size_t)ROWS * HID;       // 4,096,000 (also partial p0)
    float* ybuf   = wsf + off; off += (size_t)ROWS * HCOL;      // 16,384,000
    float* pb1    = wsf + off; off += (size_t)ROWS * HID;       // 4,096,000 (partial p1)
    float* lsb    = wsf + off; off += (size_t)ROWS * HEADS;     // 256,000
    float* ldb    = wsf + off; off += (size_t)ROWS * HEADS;     // 256,000
    float* wab    = wsf + off; off += NL * HCOL;                // 1,280
    float* wdb    = wsf + off; off += NL * HCOL;                // 1,280
    float* gib    = wsf + off; off += GOSZ;                     // 12,288
    float* hTb    = wsf + off; off += 256;
    int* ib = (int*)(wsf + off);
    int* src_e    = ib;          ib += EP;
    int* dst_e    = ib;          ib += EP;
    int* rowptr_p = ib;          ib += NNODE + 1;
    int* csr_src  = ib;          ib += EPAD;
    int* deg      = ib;          ib += NNODE;
    int* fill     = ib;          ib += NNODE;

    // gi partials alias ybuf (dead after GAT layers): (500+10)*12288 floats << 16.38M
    float* gip  = ybuf;
    float* gip2 = ybuf + (size_t)KSPLIT * GOSZ;

    k_build_edges<<<(EP + 255) / 256, 256, 0, stream>>>(eidx, src_e, dst_e, deg, fill);
    k_csr_count<<<(EP + 255) / 256, 256, 0, stream>>>(dst_e, deg);
    k_csr_scan<<<1, 256, 0, stream>>>(deg, rowptr_p);
    k_csr_fill<<<(EP + 255) / 256, 256, 0, stream>>>(src_e, dst_e, rowptr_p, fill, csr_src);
    k_pad_fill<<<(NNODE + 255) / 256, 256, 0, stream>>>(rowptr_p, deg, csr_src);

    k_wa<<<10, 256, 0, stream>>>(Wg, a_src, a_dst, wab, wdb);

    k_input_fc<<<ROWS * 16 / 256, 256, 0, stream>>>(
        x_seq, (const float4*)W_in, (const float4*)b_in,
        (const float4*)wab, (const float4*)wdb, (float4*)x0, (float4*)lsb, (float4*)ldb);

    for (int l = 0; l < NL; l++) {
        k_aggx<<<ROWS / 16, 256, 0, stream>>>(
            (const float4*)x0, (const float4*)lsb, (const float4*)ldb, rowptr_p, csr_src, deg,
            (float4*)ybuf);
        // K-split y@W': partial 0 overwrites x0 (dead after aggx), partial 1 -> pb1
        k_ygemm2<<<dim3(ROWS / 128, 2), 128, 0, stream>>>(
            (const float4*)ybuf, Wg + (size_t)l * HID * HCOL, x0, pb1);
        const float4* wa_next = (l + 1 < NL) ? (const float4*)(wab + (size_t)(l + 1) * HCOL) : nullptr;
        const float4* wd_next = (l + 1 < NL) ? (const float4*)(wdb + (size_t)(l + 1) * HCOL) : nullptr;
        k_ycomb<<<ROWS * 16 / 256, 256, 0, stream>>>(
            x0, pb1, bg + (size_t)l * HID, wa_next, wd_next, x0, (float4*)lsb, (float4*)ldb);
    }

    k_gi_gemm<<<KSPLIT, 256, 0, stream>>>(x0, W_ih, gip);
    k_gi_reduce1<<<dim3(GOSZ / 256, 10), 256, 0, stream>>>(gip, gip2);
    k_gi_reduce2<<<GOSZ / 256, 256, 0, stream>>>(gip2, b_ih, gib);
    k_gru<<<1, 256, 0, stream>>>(gib, W_hh, b_hh, hTb);
    k_final<<<(NB * NNODE + 255) / 256, 256, 0, stream>>>(hTb, W_fc, b_fc, out);
}

// Round 15
// 632.243 us; speedup vs baseline: 1.0681x; 1.0321x over previous
//
#include <hip/hip_runtime.h>
#include <math.h>

#define NB 4
#define TT 16
#define NNODE 1000
#define FIN 8
#define EE 8000
#define EP 9000          // E + N self loops
#define EPAD 16384       // max padded edges (pad rows to mult of 8)
#define HID 64
#define HEADS 4
#define NL 5
#define GG (NB*TT)       // 64 graphs
#define ROWS (GG*NNODE)  // 64000
#define HCOL (HEADS*HID) // 256
#define KGI (NNODE*HID)  // 64000
#define GOUT 192         // 3*HID
#define GIK 128          // K-slice per gi-gemm block
#define KSPLIT (KGI/GIK) // 500 partial slabs
#define GOSZ (GG*GOUT)   // 12288

// ---------------- edge prep ----------------
__global__ void k_build_edges(const int* __restrict__ eidx, int* __restrict__ src_e,
                              int* __restrict__ dst_e, int* __restrict__ deg, int* __restrict__ fill) {
    int i = blockIdx.x * blockDim.x + threadIdx.x;
    if (i < EP) {
        int s, d;
        if (i < EE) { s = eidx[i]; d = eidx[EE + i]; }
        else { s = i - EE; d = i - EE; }
        src_e[i] = s; dst_e[i] = d;
    }
    if (i < NNODE) { deg[i] = 0; fill[i] = 0; }
}

__global__ void k_csr_count(const int* __restrict__ dst_e, int* __restrict__ deg) {
    int i = blockIdx.x * blockDim.x + threadIdx.x;
    if (i < EP) atomicAdd(&deg[dst_e[i]], 1);
}

// parallel inclusive scan of PADDED degrees (pad to multiple of 8)
__global__ __launch_bounds__(256) void k_csr_scan(const int* __restrict__ deg, int* __restrict__ rowptr_p) {
    __shared__ int s[1024];
    int tid = threadIdx.x;
    for (int i = tid; i < 1024; i += 256) s[i] = (i < NNODE) ? ((deg[i] + 7) & ~7) : 0;
    __syncthreads();
    for (int off = 1; off < 1024; off <<= 1) {
        int t[4];
        #pragma unroll
        for (int q = 0; q < 4; q++) { int i = tid + 256 * q; t[q] = (i >= off) ? s[i - off] : 0; }
        __syncthreads();
        #pragma unroll
        for (int q = 0; q < 4; q++) { int i = tid + 256 * q; s[i] += t[q]; }
        __syncthreads();
    }
    for (int i = tid; i < NNODE; i += 256) rowptr_p[i + 1] = s[i];
    if (tid == 0) rowptr_p[0] = 0;
}

__global__ void k_csr_fill(const int* __restrict__ src_e, const int* __restrict__ dst_e,
                           const int* __restrict__ rowptr_p, int* __restrict__ fill,
                           int* __restrict__ csr_src) {
    int i = blockIdx.x * blockDim.x + threadIdx.x;
    if (i < EP) {
        int d = dst_e[i];
        int pos = atomicAdd(&fill[d], 1);
        csr_src[rowptr_p[d] + pos] = src_e[i];
    }
}

// fill pad slots with dummy self-edges (they get alpha = 0 in the fused agg)
__global__ void k_pad_fill(const int* __restrict__ rowptr_p, const int* __restrict__ deg,
                           int* __restrict__ csr_src) {
    int n = blockIdx.x * blockDim.x + threadIdx.x;
    if (n >= NNODE) return;
    int rs = rowptr_p[n], re = rowptr_p[n + 1];
    for (int j = rs + deg[n]; j < re; j++) csr_src[j] = n;
}

// ---------------- precompute wa/wd: wa[l][j][h] = sum_c W_l[j, h*64+c] * a_src[l,h,c] ----------------
__global__ void k_wa(const float* __restrict__ Wg, const float* __restrict__ a_src,
                     const float* __restrict__ a_dst, float* __restrict__ wa, float* __restrict__ wd) {
    int t = blockIdx.x * 256 + threadIdx.x;      // 2*NL*HID*HEADS = 2560
    if (t >= 2 * NL * HID * HEADS) return;
    int kind = t >= NL * HID * HEADS;
    int u = t - kind * NL * HID * HEADS;
    int l = u >> 8;
    int rem = u & 255;
    int j = rem >> 2, hd = rem & 3;
    const float* a = (kind ? a_dst : a_src) + (size_t)l * HCOL + hd * HID;
    const float* Wl = Wg + (size_t)l * HID * HCOL + (size_t)j * HCOL + hd * HID;
    float acc = 0.f;
    #pragma unroll 8
    for (int c = 0; c < HID; c++) acc += Wl[c] * a[c];
    float* out = kind ? wd : wa;
    out[(size_t)l * HCOL + j * 4 + hd] = acc;
}

// ---------------- input projection + fused layer-0 ls/ld ----------------
__global__ void k_input_fc(const float* __restrict__ xseq, const float4* __restrict__ Win4,
                           const float4* __restrict__ b_in4, const float4* __restrict__ wa04,
                           const float4* __restrict__ wd04, float4* __restrict__ x0,
                           float4* __restrict__ ls4, float4* __restrict__ ld4) {
    int idx = blockIdx.x * 256 + threadIdx.x;   // ROWS*16 threads
    int r = idx >> 4, c4 = idx & 15;
    float4 acc = b_in4[c4];
    #pragma unroll
    for (int k = 0; k < FIN; k++) {
        float xv = xseq[r * FIN + k];
        float4 w = Win4[k * 16 + c4];
        acc.x += xv * w.x; acc.y += xv * w.y; acc.z += xv * w.z; acc.w += xv * w.w;
    }
    x0[idx] = acc;
    float xr[4] = {acc.x, acc.y, acc.z, acc.w};
    float4 pls = make_float4(0.f, 0.f, 0.f, 0.f);
    float4 pld = make_float4(0.f, 0.f, 0.f, 0.f);
    #pragma unroll
    for (int jj = 0; jj < 4; jj++) {
        float4 wa_j = wa04[c4 * 4 + jj];
        float4 wd_j = wd04[c4 * 4 + jj];
        pls.x += xr[jj] * wa_j.x; pls.y += xr[jj] * wa_j.y;
        pls.z += xr[jj] * wa_j.z; pls.w += xr[jj] * wa_j.w;
        pld.x += xr[jj] * wd_j.x; pld.y += xr[jj] * wd_j.y;
        pld.z += xr[jj] * wd_j.z; pld.w += xr[jj] * wd_j.w;
    }
    #pragma unroll
    for (int o = 1; o < 16; o <<= 1) {
        pls.x += __shfl_xor(pls.x, o, 64); pls.y += __shfl_xor(pls.y, o, 64);
        pls.z += __shfl_xor(pls.z, o, 64); pls.w += __shfl_xor(pls.w, o, 64);
        pld.x += __shfl_xor(pld.x, o, 64); pld.y += __shfl_xor(pld.y, o, 64);
        pld.z += __shfl_xor(pld.z, o, 64); pld.w += __shfl_xor(pld.w, o, 64);
    }
    if (c4 == 0) {
        ls4[r] = pls;
        ld4[r] = pld;
    }
}

// ---------------- fused softmax + x-aggregate: y[n][h*64+c] = sum_j alpha_hj x[s_j][c] ----------------
__global__ __launch_bounds__(256) void k_aggx(const float4* __restrict__ x4, const float4* __restrict__ ls4,
                                              const float4* __restrict__ ld4, const int* __restrict__ rowptr_p,
                                              const int* __restrict__ csr_src, const int* __restrict__ deg,
                                              float4* __restrict__ y4) {
    __shared__ float s_e[4][4][4 * 68];   // [wave][node][head*68 + j], j < 64
    __shared__ int   s_src[4][4][64];     // [wave][node][j]
    __shared__ float s_den[4][4][4];      // [wave][node][head]
    int b = blockIdx.x;                   // 0..3999
    int xcd = b & 7, s = b >> 3;          // XCD round-robin
    int tid = threadIdx.x;
    int wid = tid >> 6, lane = tid & 63;
    int w = s * 4 + wid;                  // 0..1999 per XCD
    int g = xcd + 8 * (w / 250);
    int n0 = (w % 250) * 4;
    int nsub = lane >> 4;                 // node slot 0..3 (softmax phase)
    int j0 = lane & 15;                   // edge slot within group
    int n_s = n0 + nsub;
    int rs = rowptr_p[n_s];
    int dgp = rowptr_p[n_s + 1] - rs;     // multiple of 8
    int dg = deg[n_s];
    int dg16 = (dgp + 15) & ~15;
    if (dg16 > 64) dg16 = 64;             // safety clamp
    if (dgp > 64) dgp = 64;
    float4 ldv = ld4[(size_t)g * NNODE + n_s];
    const float4* lsg = ls4 + (size_t)g * NNODE;

    // --- pass A: logits + running max ---
    float4 mx = make_float4(-1e30f, -1e30f, -1e30f, -1e30f);
    for (int base = 0; base < dg16; base += 16) {
        int j = base + j0;
        int sv = n_s;
        if (j < dgp) sv = csr_src[rs + j];
        s_src[wid][nsub][j] = sv;
        float4 lo = make_float4(-1e30f, -1e30f, -1e30f, -1e30f);
        if (j < dg) {
            float4 t = lsg[sv];
            t.x += ldv.x; t.y += ldv.y; t.z += ldv.z; t.w += ldv.w;
            t.x = fmaxf(t.x, 0.2f * t.x); t.y = fmaxf(t.y, 0.2f * t.y);
            t.z = fmaxf(t.z, 0.2f * t.z); t.w = fmaxf(t.w, 0.2f * t.w);
            lo = t;
            mx.x = fmaxf(mx.x, lo.x); mx.y = fmaxf(mx.y, lo.y);
            mx.z = fmaxf(mx.z, lo.z); mx.w = fmaxf(mx.w, lo.w);
        }
        s_e[wid][nsub][0 * 68 + j] = lo.x;
        s_e[wid][nsub][1 * 68 + j] = lo.y;
        s_e[wid][nsub][2 * 68 + j] = lo.z;
        s_e[wid][nsub][3 * 68 + j] = lo.w;
    }
    #pragma unroll
    for (int o = 1; o < 16; o <<= 1) {
        mx.x = fmaxf(mx.x, __shfl_xor(mx.x, o, 64));
        mx.y = fmaxf(mx.y, __shfl_xor(mx.y, o, 64));
        mx.z = fmaxf(mx.z, __shfl_xor(mx.z, o, 64));
        mx.w = fmaxf(mx.w, __shfl_xor(mx.w, o, 64));
    }
    // --- pass B: exp + denominator; store unnormalized e (zeros for j >= dg) ---
    float4 den = make_float4(0.f, 0.f, 0.f, 0.f);
    for (int base = 0; base < dg16; base += 16) {
        int j = base + j0;
        float4 e = make_float4(0.f, 0.f, 0.f, 0.f);
        if (j < dg) {
            e.x = expf(s_e[wid][nsub][0 * 68 + j] - mx.x);
            e.y = expf(s_e[wid][nsub][1 * 68 + j] - mx.y);
            e.z = expf(s_e[wid][nsub][2 * 68 + j] - mx.z);
            e.w = expf(s_e[wid][nsub][3 * 68 + j] - mx.w);
        }
        den.x += e.x; den.y += e.y; den.z += e.z; den.w += e.w;
        s_e[wid][nsub][0 * 68 + j] = e.x;
        s_e[wid][nsub][1 * 68 + j] = e.y;
        s_e[wid][nsub][2 * 68 + j] = e.z;
        s_e[wid][nsub][3 * 68 + j] = e.w;
    }
    #pragma unroll
    for (int o = 1; o < 16; o <<= 1) {
        den.x += __shfl_xor(den.x, o, 64);
        den.y += __shfl_xor(den.y, o, 64);
        den.z += __shfl_xor(den.z, o, 64);
        den.w += __shfl_xor(den.w, o, 64);
    }
    if (j0 == 0) {
        s_den[wid][nsub][0] = den.x;
        s_den[wid][nsub][1] = den.y;
        s_den[wid][nsub][2] = den.z;
        s_den[wid][nsub][3] = den.w;
    }

    // --- gather phase: lane = head*16 + c4; x-row gathers, all nodes before epilogue ---
    int head = lane >> 4, c4 = lane & 15;
    const float4* xg = x4 + (size_t)g * NNODE * 16 + c4;
    float4 acc[4];
    #pragma unroll
    for (int nn = 0; nn < 4; nn++) acc[nn] = make_float4(0.f, 0.f, 0.f, 0.f);
    #pragma unroll
    for (int nn = 0; nn < 4; nn++) {
        int dgc = __shfl(dgp, nn * 16, 64);
        const float* ep = &s_e[wid][nn][head * 68];
        const int* sp = &s_src[wid][nn][0];
        for (int q = 0; q < dgc; q += 8) {
            int sj[8]; float av[8];
            #pragma unroll
            for (int u = 0; u < 8; u++) {
                sj[u] = sp[q + u];
                av[u] = ep[q + u];
            }
            float4 xv[8];
            #pragma unroll
            for (int u = 0; u < 8; u++) xv[u] = xg[(size_t)sj[u] * 16];
            #pragma unroll
            for (int u = 0; u < 8; u++) {
                acc[nn].x += av[u] * xv[u].x;
                acc[nn].y += av[u] * xv[u].y;
                acc[nn].z += av[u] * xv[u].z;
                acc[nn].w += av[u] * xv[u].w;
            }
        }
    }
    #pragma unroll
    for (int nn = 0; nn < 4; nn++) {
        float inv = 1.f / (s_den[wid][nn][head] + 1e-16f);
        float4 a = acc[nn];
        a.x *= inv; a.y *= inv; a.z *= inv; a.w *= inv;
        y4[((size_t)g * NNODE + n0 + nn) * 64 + lane] = a;   // y[n][h*64+c] as float4
    }
}

// ---------------- y @ W' K-split GEMM: grid (500, 2), 128 thr, 128x64 tile, 8x8/thread ----------------
__global__ __launch_bounds__(128) void k_ygemm2(const float4* __restrict__ y4, const float* __restrict__ W,
                                                float* __restrict__ p0, float* __restrict__ p1) {
    __shared__ float ys[64 * 132];    // [kk_local][row], pitch 132
    int tid = threadIdx.x;            // 0..127
    int r0 = blockIdx.x * 128;
    int by = blockIdx.y;              // 0..1
    int rg = tid >> 3;                // 0..15 -> rows rg*8..+7
    int cg = tid & 7;                 // 0..7  -> cols cg*8..+7
    float acc[8][8];
    #pragma unroll
    for (int i = 0; i < 8; i++)
        #pragma unroll
        for (int j = 0; j < 8; j++) acc[i][j] = 0.f;

    for (int ck = 0; ck < 2; ck++) {
        __syncthreads();
        #pragma unroll
        for (int it = 0; it < 16; it++) {
            float4 v = y4[(size_t)(r0 + tid) * 64 + by * 32 + ck * 16 + it];
            int kq = it * 4;
            ys[(kq + 0) * 132 + tid] = v.x;
            ys[(kq + 1) * 132 + tid] = v.y;
            ys[(kq + 2) * 132 + tid] = v.z;
            ys[(kq + 3) * 132 + tid] = v.w;
        }
        __syncthreads();
        int hd = by * 2 + ck;                       // head for this 64-kk sub-chunk
        const float* wp = W + (size_t)hd * 64 + cg * 8;
        for (int kk = 0; kk < 64; kk++) {
            float4 w0 = *reinterpret_cast<const float4*>(&wp[(size_t)kk * HCOL]);
            float4 w1 = *reinterpret_cast<const float4*>(&wp[(size_t)kk * HCOL + 4]);
            float4 xv0 = *reinterpret_cast<const float4*>(&ys[kk * 132 + rg * 8]);
            float4 xv1 = *reinterpret_cast<const float4*>(&ys[kk * 132 + rg * 8 + 4]);
            float xr[8] = {xv0.x, xv0.y, xv0.z, xv0.w, xv1.x, xv1.y, xv1.z, xv1.w};
            #pragma unroll
            for (int i = 0; i < 8; i++) {
                acc[i][0] += xr[i] * w0.x; acc[i][1] += xr[i] * w0.y;
                acc[i][2] += xr[i] * w0.z; acc[i][3] += xr[i] * w0.w;
                acc[i][4] += xr[i] * w1.x; acc[i][5] += xr[i] * w1.y;
                acc[i][6] += xr[i] * w1.z; acc[i][7] += xr[i] * w1.w;
            }
        }
    }
    float* pb = by ? p1 : p0;
    #pragma unroll
    for (int i = 0; i < 8; i++) {
        int row = r0 + rg * 8 + i;
        *reinterpret_cast<float4*>(&pb[(size_t)row * 64 + cg * 8]) =
            make_float4(acc[i][0], acc[i][1], acc[i][2], acc[i][3]);
        *reinterpret_cast<float4*>(&pb[(size_t)row * 64 + cg * 8 + 4]) =
            make_float4(acc[i][4], acc[i][5], acc[i][6], acc[i][7]);
    }
}

// ---------------- combine partials + bias + ELU -> x0; fused next-layer ls/ld ----------------
__global__ void k_ycomb(const float* __restrict__ p0, const float* __restrict__ p1,
                        const float* __restrict__ bg, const float4* __restrict__ wa4,
                        const float4* __restrict__ wd4, float* __restrict__ xout,
                        float4* __restrict__ ls4, float4* __restrict__ ld4) {
    int idx = blockIdx.x * 256 + threadIdx.x;   // ROWS*16
    int r = idx >> 4, c4 = idx & 15;
    float4 a = *reinterpret_cast<const float4*>(&p0[(size_t)r * 64 + c4 * 4]);
    float4 b = *reinterpret_cast<const float4*>(&p1[(size_t)r * 64 + c4 * 4]);
    float4 bb = *reinterpret_cast<const float4*>(&bg[c4 * 4]);
    float rr[4];
    rr[0] = (a.x + b.x) * 0.25f + bb.x;
    rr[1] = (a.y + b.y) * 0.25f + bb.y;
    rr[2] = (a.z + b.z) * 0.25f + bb.z;
    rr[3] = (a.w + b.w) * 0.25f + bb.w;
    #pragma unroll
    for (int j = 0; j < 4; j++) rr[j] = rr[j] > 0.f ? rr[j] : expm1f(rr[j]);
    *reinterpret_cast<float4*>(&xout[(size_t)r * 64 + c4 * 4]) =
        make_float4(rr[0], rr[1], rr[2], rr[3]);
    if (wa4) {
        float4 pls = make_float4(0.f, 0.f, 0.f, 0.f);
        float4 pld = make_float4(0.f, 0.f, 0.f, 0.f);
        #pragma unroll
        for (int jj = 0; jj < 4; jj++) {
            float4 wa_j = wa4[c4 * 4 + jj];
            float4 wd_j = wd4[c4 * 4 + jj];
            pls.x += rr[jj] * wa_j.x; pls.y += rr[jj] * wa_j.y;
            pls.z += rr[jj] * wa_j.z; pls.w += rr[jj] * wa_j.w;
            pld.x += rr[jj] * wd_j.x; pld.y += rr[jj] * wd_j.y;
            pld.z += rr[jj] * wd_j.z; pld.w += rr[jj] * wd_j.w;
        }
        #pragma unroll
        for (int o = 1; o < 16; o <<= 1) {
            pls.x += __shfl_xor(pls.x, o, 64); pls.y += __shfl_xor(pls.y, o, 64);
            pls.z += __shfl_xor(pls.z, o, 64); pls.w += __shfl_xor(pls.w, o, 64);
            pld.x += __shfl_xor(pld.x, o, 64); pld.y += __shfl_xor(pld.y, o, 64);
            pld.z += __shfl_xor(pld.z, o, 64); pld.w += __shfl_xor(pld.w, o, 64);
        }
        if (c4 == 0) {
            ls4[r] = pls;
            ld4[r] = pld;
        }
    }
}

// ---------------- GRU input GEMM: 500 K-slices, full 64x192 tile/block, no atomics ----------------
__global__ __launch_bounds__(256) void k_gi_gemm(const float* __restrict__ x, const float* __restrict__ W_ih,
                                                 float* __restrict__ gip) {
    __shared__ float xs[32 * 68];    // [kk][row], pitch 68
    __shared__ float ws[32 * 196];   // [kk][col 0..191], pitch 196
    int k0 = blockIdx.x * GIK;
    int tid = threadIdx.x;
    int lane = tid & 63;
    int wv = tid >> 6;
    int tx = tid & 15, ty = tid >> 4;
    float4 accs[4][3];
    #pragma unroll
    for (int i = 0; i < 4; i++)
        #pragma unroll
        for (int j = 0; j < 3; j++) accs[i][j] = make_float4(0.f, 0.f, 0.f, 0.f);

    for (int kt = 0; kt < GIK / 32; kt++) {
        int kb = k0 + kt * 32;
        #pragma unroll
        for (int it = 0; it < 2; it++) {
            int kq = wv + 4 * it;
            float4 v = *reinterpret_cast<const float4*>(&x[(size_t)lane * KGI + kb + kq * 4]);
            int k = kq * 4;
            xs[(k + 0) * 68 + lane] = v.x;
            xs[(k + 1) * 68 + lane] = v.y;
            xs[(k + 2) * 68 + lane] = v.z;
            xs[(k + 3) * 68 + lane] = v.w;
        }
        #pragma unroll
        for (int cg = 0; cg < 3; cg++) {
            #pragma unroll
            for (int it = 0; it < 2; it++) {
                int kq = wv + 4 * it;
                int c = cg * 64 + lane;
                float4 v = *reinterpret_cast<const float4*>(&W_ih[(size_t)c * KGI + kb + kq * 4]);
                int k = kq * 4;
                ws[(k + 0) * 196 + c] = v.x;
                ws[(k + 1) * 196 + c] = v.y;
                ws[(k + 2) * 196 + c] = v.z;
                ws[(k + 3) * 196 + c] = v.w;
            }
        }
        __syncthreads();
        for (int kk = 0; kk < 32; kk++) {
            float4 xv = *reinterpret_cast<const float4*>(&xs[kk * 68 + ty * 4]);
            float4 w0 = *reinterpret_cast<const float4*>(&ws[kk * 196 + tx * 4]);
            float4 w1 = *reinterpret_cast<const float4*>(&ws[kk * 196 + 64 + tx * 4]);
            float4 w2 = *reinterpret_cast<const float4*>(&ws[kk * 196 + 128 + tx * 4]);
            #pragma unroll
            for (int i = 0; i < 4; i++) {
                float xi = (i == 0) ? xv.x : (i == 1) ? xv.y : (i == 2) ? xv.z : xv.w;
                accs[i][0].x += xi * w0.x; accs[i][0].y += xi * w0.y; accs[i][0].z += xi * w0.z; accs[i][0].w += xi * w0.w;
                accs[i][1].x += xi * w1.x; accs[i][1].y += xi * w1.y; accs[i][1].z += xi * w1.z; accs[i][1].w += xi * w1.w;
                accs[i][2].x += xi * w2.x; accs[i][2].y += xi * w2.y; accs[i][2].z += xi * w2.z; accs[i][2].w += xi * w2.w;
            }
        }
        __syncthreads();
    }
    float* out = gip + (size_t)blockIdx.x * GOSZ;
    #pragma unroll
    for (int i = 0; i < 4; i++)
        #pragma unroll
        for (int j = 0; j < 3; j++)
            *reinterpret_cast<float4*>(&out[(ty * 4 + i) * GOUT + j * 64 + tx * 4]) = accs[i][j];
}

__global__ void k_gi_reduce1(const float* __restrict__ gip, float* __restrict__ gip2) {
    int idx = blockIdx.x * 256 + threadIdx.x;     // 0..GOSZ-1
    const float* p = gip + (size_t)blockIdx.y * 50 * GOSZ + idx;
    float a = 0.f;
    #pragma unroll 5
    for (int s = 0; s < 50; s++) a += p[(size_t)s * GOSZ];
    gip2[blockIdx.y * GOSZ + idx] = a;
}

__global__ void k_gi_reduce2(const float* __restrict__ gip2, const float* __restrict__ b_ih,
                             float* __restrict__ gi) {
    int idx = blockIdx.x * 256 + threadIdx.x;
    float a = b_ih[idx % GOUT];
    #pragma unroll
    for (int y = 0; y < 10; y++) a += gip2[(size_t)y * GOSZ + idx];
    gi[idx] = a;
}

// ---------------- GRU scan: one block per batch, W_hh row in registers, LDS broadcast hs ----------------
__global__ __launch_bounds__(192) void k_gru(const float* __restrict__ gi, const float* __restrict__ W_hh,
                                             const float* __restrict__ b_hh, float* __restrict__ hT) {
    __shared__ float hs[64];
    __shared__ float gh[192];
    int j = threadIdx.x;      // 0..191
    int b = blockIdx.x;       // 0..3
    float wrow[64];
    #pragma unroll
    for (int q = 0; q < 16; q++) {
        float4 v = *reinterpret_cast<const float4*>(&W_hh[(size_t)j * 64 + q * 4]);
        wrow[q * 4 + 0] = v.x; wrow[q * 4 + 1] = v.y;
        wrow[q * 4 + 2] = v.z; wrow[q * 4 + 3] = v.w;
    }
    float bj = b_hh[j];
    if (j < 64) hs[j] = 0.f;
    __syncthreads();
    for (int t = 0; t < TT; t++) {
        float a0 = 0.f, a1 = 0.f, a2 = 0.f, a3 = 0.f;
        #pragma unroll
        for (int q = 0; q < 16; q++) {
            float4 h4 = *reinterpret_cast<const float4*>(&hs[q * 4]);   // broadcast read
            a0 += h4.x * wrow[q * 4 + 0];
            a1 += h4.y * wrow[q * 4 + 1];
            a2 += h4.z * wrow[q * 4 + 2];
            a3 += h4.w * wrow[q * 4 + 3];
        }
        gh[j] = bj + ((a0 + a1) + (a2 + a3));
        __syncthreads();
        if (j < 64) {
            int row = (b * TT + t) * GOUT;
            float ir = gi[row + j], iz = gi[row + 64 + j], in_ = gi[row + 128 + j];
            float r = 1.f / (1.f + expf(-(ir + gh[j])));
            float z = 1.f / (1.f + expf(-(iz + gh[64 + j])));
            float nv = tanhf(in_ + r * gh[128 + j]);
            hs[j] = (1.f - z) * nv + z * hs[j];
        }
        __syncthreads();
    }
    if (j < 64) hT[b * 64 + j] = hs[j];
}

// ---------------- final FC ----------------
__global__ void k_final(const float* __restrict__ hT, const float* __restrict__ W_fc,
                        const float* __restrict__ b_fc, float* __restrict__ out) {
    int idx = blockIdx.x * 256 + threadIdx.x;
    if (idx >= NB * NNODE) return;
    int b = idx / NNODE, n = idx % NNODE;
    float acc = b_fc[n];
    #pragma unroll
    for (int c = 0; c < HID; c++) acc += hT[b * HID + c] * W_fc[c * NNODE + n];
    out[idx] = acc;
}

extern "C" void kernel_launch(void* const* d_in, const int* in_sizes, int n_in,
                              void* d_out, int out_size, void* d_ws, size_t ws_size,
                              hipStream_t stream) {
    const float* x_seq  = (const float*)d_in[0];
    const int*   eidx   = (const int*)  d_in[1];
    // d_in[2] edge_weight: unused by GATConv
    const float* W_in   = (const float*)d_in[3];
    const float* b_in   = (const float*)d_in[4];
    const float* Wg     = (const float*)d_in[5];
    const float* a_src  = (const float*)d_in[6];
    const float* a_dst  = (const float*)d_in[7];
    const float* bg     = (const float*)d_in[8];
    const float* W_ih   = (const float*)d_in[9];
    const float* W_hh   = (const float*)d_in[10];
    const float* b_ih   = (const float*)d_in[11];
    const float* b_hh   = (const float*)d_in[12];
    const float* W_fc   = (const float*)d_in[13];
    const float* b_fc   = (const float*)d_in[14];
    float* out = (float*)d_out;

    float* wsf = (float*)d_ws;
    size_t off = 0;
    float* x0     = wsf + off; off += (size_t)ROWS * HID;       // 4,096,000 (also partial p0)
    float* ybuf   = wsf + off; off += (size_t)ROWS * HCOL;      // 16,384,000
    float* pb1    = wsf + off; off += (size_t)ROWS * HID;       // 4,096,000 (partial p1)
    float* lsb    = wsf + off; off += (size_t)ROWS * HEADS;     // 256,000
    float* ldb    = wsf + off; off += (size_t)ROWS * HEADS;     // 256,000
    float* wab    = wsf + off; off += NL * HCOL;                // 1,280
    float* wdb    = wsf + off; off += NL * HCOL;                // 1,280
    float* gib    = wsf + off; off += GOSZ;                     // 12,288
    float* hTb    = wsf + off; off += 256;
    int* ib = (int*)(wsf + off);
    int* src_e    = ib;          ib += EP;
    int* dst_e    = ib;          ib += EP;
    int* rowptr_p = ib;          ib += NNODE + 1;
    int* csr_src  = ib;          ib += EPAD;
    int* deg      = ib;          ib += NNODE;
    int* fill     = ib;          ib += NNODE;

    // gi partials alias ybuf (dead after GAT layers): (500+10)*12288 floats << 16.38M
    float* gip  = ybuf;
    float* gip2 = ybuf + (size_t)KSPLIT * GOSZ;

    k_build_edges<<<(EP + 255) / 256, 256, 0, stream>>>(eidx, src_e, dst_e, deg, fill);
    k_csr_count<<<(EP + 255) / 256, 256, 0, stream>>>(dst_e, deg);
    k_csr_scan<<<1, 256, 0, stream>>>(deg, rowptr_p);
    k_csr_fill<<<(EP + 255) / 256, 256, 0, stream>>>(src_e, dst_e, rowptr_p, fill, csr_src);
    k_pad_fill<<<(NNODE + 255) / 256, 256, 0, stream>>>(rowptr_p, deg, csr_src);

    k_wa<<<10, 256, 0, stream>>>(Wg, a_src, a_dst, wab, wdb);

    k_input_fc<<<ROWS * 16 / 256, 256, 0, stream>>>(
        x_seq, (const float4*)W_in, (const float4*)b_in,
        (const float4*)wab, (const float4*)wdb, (float4*)x0, (float4*)lsb, (float4*)ldb);

    for (int l = 0; l < NL; l++) {
        k_aggx<<<ROWS / 16, 256, 0, stream>>>(
            (const float4*)x0, (const float4*)lsb, (const float4*)ldb, rowptr_p, csr_src, deg,
            (float4*)ybuf);
        k_ygemm2<<<dim3(ROWS / 128, 2), 128, 0, stream>>>(
            (const float4*)ybuf, Wg + (size_t)l * HID * HCOL, x0, pb1);
        const float4* wa_next = (l + 1 < NL) ? (const float4*)(wab + (size_t)(l + 1) * HCOL) : nullptr;
        const float4* wd_next = (l + 1 < NL) ? (const float4*)(wdb + (size_t)(l + 1) * HCOL) : nullptr;
        k_ycomb<<<ROWS * 16 / 256, 256, 0, stream>>>(
            x0, pb1, bg + (size_t)l * HID, wa_next, wd_next, x0, (float4*)lsb, (float4*)ldb);
    }

    k_gi_gemm<<<KSPLIT, 256, 0, stream>>>(x0, W_ih, gip);
    k_gi_reduce1<<<dim3(GOSZ / 256, 10), 256, 0, stream>>>(gip, gip2);
    k_gi_reduce2<<<GOSZ / 256, 256, 0, stream>>>(gip2, b_ih, gib);
    k_gru<<<4, 192, 0, stream>>>(gib, W_hh, b_hh, hTb);
    k_final<<<(NB * NNODE + 255) / 256, 256, 0, stream>>>(hTb, W_fc, b_fc, out);
}

// Round 16
// 601.965 us; speedup vs baseline: 1.1218x; 1.0503x over previous
//
#include <hip/hip_runtime.h>
#include <math.h>

#define NB 4
#define TT 16
#define NNODE 1000
#define FIN 8
#define EE 8000
#define EP 9000          // E + N self loops
#define EPAD 16384       // max padded edges (pad rows to mult of 8)
#define HID 64
#define HEADS 4
#define NL 5
#define GG (NB*TT)       // 64 graphs
#define ROWS (GG*NNODE)  // 64000
#define HCOL (HEADS*HID) // 256
#define KGI (NNODE*HID)  // 64000
#define GOUT 192         // 3*HID
#define GIK 128          // K-slice per gi-gemm block
#define KSPLIT (KGI/GIK) // 500 partial slabs
#define GOSZ (GG*GOUT)   // 12288

// ---------------- edge prep ----------------
__global__ void k_build_edges(const int* __restrict__ eidx, int* __restrict__ src_e,
                              int* __restrict__ dst_e, int* __restrict__ deg, int* __restrict__ fill) {
    int i = blockIdx.x * blockDim.x + threadIdx.x;
    if (i < EP) {
        int s, d;
        if (i < EE) { s = eidx[i]; d = eidx[EE + i]; }
        else { s = i - EE; d = i - EE; }
        src_e[i] = s; dst_e[i] = d;
    }
    if (i < NNODE) { deg[i] = 0; fill[i] = 0; }
}

__global__ void k_csr_count(const int* __restrict__ dst_e, int* __restrict__ deg) {
    int i = blockIdx.x * blockDim.x + threadIdx.x;
    if (i < EP) atomicAdd(&deg[dst_e[i]], 1);
}

// parallel inclusive scan of PADDED degrees (pad to multiple of 8)
__global__ __launch_bounds__(256) void k_csr_scan(const int* __restrict__ deg, int* __restrict__ rowptr_p) {
    __shared__ int s[1024];
    int tid = threadIdx.x;
    for (int i = tid; i < 1024; i += 256) s[i] = (i < NNODE) ? ((deg[i] + 7) & ~7) : 0;
    __syncthreads();
    for (int off = 1; off < 1024; off <<= 1) {
        int t[4];
        #pragma unroll
        for (int q = 0; q < 4; q++) { int i = tid + 256 * q; t[q] = (i >= off) ? s[i - off] : 0; }
        __syncthreads();
        #pragma unroll
        for (int q = 0; q < 4; q++) { int i = tid + 256 * q; s[i] += t[q]; }
        __syncthreads();
    }
    for (int i = tid; i < NNODE; i += 256) rowptr_p[i + 1] = s[i];
    if (tid == 0) rowptr_p[0] = 0;
}

__global__ void k_csr_fill(const int* __restrict__ src_e, const int* __restrict__ dst_e,
                           const int* __restrict__ rowptr_p, int* __restrict__ fill,
                           int* __restrict__ csr_src) {
    int i = blockIdx.x * blockDim.x + threadIdx.x;
    if (i < EP) {
        int d = dst_e[i];
        int pos = atomicAdd(&fill[d], 1);
        csr_src[rowptr_p[d] + pos] = src_e[i];
    }
}

// fill pad slots with dummy self-edges (they get alpha = 0 in the fused agg)
__global__ void k_pad_fill(const int* __restrict__ rowptr_p, const int* __restrict__ deg,
                           int* __restrict__ csr_src) {
    int n = blockIdx.x * blockDim.x + threadIdx.x;
    if (n >= NNODE) return;
    int rs = rowptr_p[n], re = rowptr_p[n + 1];
    for (int j = rs + deg[n]; j < re; j++) csr_src[j] = n;
}

// ---------------- precompute wa/wd: wa[l][j][h] = sum_c W_l[j, h*64+c] * a_src[l,h,c] ----------------
__global__ void k_wa(const float* __restrict__ Wg, const float* __restrict__ a_src,
                     const float* __restrict__ a_dst, float* __restrict__ wa, float* __restrict__ wd) {
    int t = blockIdx.x * 256 + threadIdx.x;      // 2*NL*HID*HEADS = 2560
    if (t >= 2 * NL * HID * HEADS) return;
    int kind = t >= NL * HID * HEADS;
    int u = t - kind * NL * HID * HEADS;
    int l = u >> 8;
    int rem = u & 255;
    int j = rem >> 2, hd = rem & 3;
    const float* a = (kind ? a_dst : a_src) + (size_t)l * HCOL + hd * HID;
    const float* Wl = Wg + (size_t)l * HID * HCOL + (size_t)j * HCOL + hd * HID;
    float acc = 0.f;
    #pragma unroll 8
    for (int c = 0; c < HID; c++) acc += Wl[c] * a[c];
    float* out = kind ? wd : wa;
    out[(size_t)l * HCOL + j * 4 + hd] = acc;
}

// ---------------- input projection + fused layer-0 ls/ld ----------------
__global__ void k_input_fc(const float* __restrict__ xseq, const float4* __restrict__ Win4,
                           const float4* __restrict__ b_in4, const float4* __restrict__ wa04,
                           const float4* __restrict__ wd04, float4* __restrict__ x0,
                           float4* __restrict__ ls4, float4* __restrict__ ld4) {
    int idx = blockIdx.x * 256 + threadIdx.x;   // ROWS*16 threads
    int r = idx >> 4, c4 = idx & 15;
    float4 acc = b_in4[c4];
    #pragma unroll
    for (int k = 0; k < FIN; k++) {
        float xv = xseq[r * FIN + k];
        float4 w = Win4[k * 16 + c4];
        acc.x += xv * w.x; acc.y += xv * w.y; acc.z += xv * w.z; acc.w += xv * w.w;
    }
    x0[idx] = acc;
    float xr[4] = {acc.x, acc.y, acc.z, acc.w};
    float4 pls = make_float4(0.f, 0.f, 0.f, 0.f);
    float4 pld = make_float4(0.f, 0.f, 0.f, 0.f);
    #pragma unroll
    for (int jj = 0; jj < 4; jj++) {
        float4 wa_j = wa04[c4 * 4 + jj];
        float4 wd_j = wd04[c4 * 4 + jj];
        pls.x += xr[jj] * wa_j.x; pls.y += xr[jj] * wa_j.y;
        pls.z += xr[jj] * wa_j.z; pls.w += xr[jj] * wa_j.w;
        pld.x += xr[jj] * wd_j.x; pld.y += xr[jj] * wd_j.y;
        pld.z += xr[jj] * wd_j.z; pld.w += xr[jj] * wd_j.w;
    }
    #pragma unroll
    for (int o = 1; o < 16; o <<= 1) {
        pls.x += __shfl_xor(pls.x, o, 64); pls.y += __shfl_xor(pls.y, o, 64);
        pls.z += __shfl_xor(pls.z, o, 64); pls.w += __shfl_xor(pls.w, o, 64);
        pld.x += __shfl_xor(pld.x, o, 64); pld.y += __shfl_xor(pld.y, o, 64);
        pld.z += __shfl_xor(pld.z, o, 64); pld.w += __shfl_xor(pld.w, o, 64);
    }
    if (c4 == 0) {
        ls4[r] = pls;
        ld4[r] = pld;
    }
}

// ---------------- fused softmax + x-aggregate: y[n][h*64+c] = sum_j alpha_hj x[s_j][c] ----------------
__global__ __launch_bounds__(256) void k_aggx(const float4* __restrict__ x4, const float4* __restrict__ ls4,
                                              const float4* __restrict__ ld4, const int* __restrict__ rowptr_p,
                                              const int* __restrict__ csr_src, const int* __restrict__ deg,
                                              float4* __restrict__ y4) {
    __shared__ float s_e[4][4][4 * 68];   // [wave][node][head*68 + j], j < 64
    __shared__ int   s_src[4][4][64];     // [wave][node][j]
    __shared__ float s_den[4][4][4];      // [wave][node][head]
    int b = blockIdx.x;                   // 0..3999
    int xcd = b & 7, s = b >> 3;          // XCD round-robin
    int tid = threadIdx.x;
    int wid = tid >> 6, lane = tid & 63;
    int w = s * 4 + wid;                  // 0..1999 per XCD
    int g = xcd + 8 * (w / 250);
    int n0 = (w % 250) * 4;
    int nsub = lane >> 4;                 // node slot 0..3 (softmax phase)
    int j0 = lane & 15;                   // edge slot within group
    int n_s = n0 + nsub;
    int rs = rowptr_p[n_s];
    int dgp = rowptr_p[n_s + 1] - rs;     // multiple of 8
    int dg = deg[n_s];
    int dg16 = (dgp + 15) & ~15;
    if (dg16 > 64) dg16 = 64;             // safety clamp
    if (dgp > 64) dgp = 64;
    float4 ldv = ld4[(size_t)g * NNODE + n_s];
    const float4* lsg = ls4 + (size_t)g * NNODE;

    // --- pass A: logits + running max ---
    float4 mx = make_float4(-1e30f, -1e30f, -1e30f, -1e30f);
    for (int base = 0; base < dg16; base += 16) {
        int j = base + j0;
        int sv = n_s;
        if (j < dgp) sv = csr_src[rs + j];
        s_src[wid][nsub][j] = sv;
        float4 lo = make_float4(-1e30f, -1e30f, -1e30f, -1e30f);
        if (j < dg) {
            float4 t = lsg[sv];
            t.x += ldv.x; t.y += ldv.y; t.z += ldv.z; t.w += ldv.w;
            t.x = fmaxf(t.x, 0.2f * t.x); t.y = fmaxf(t.y, 0.2f * t.y);
            t.z = fmaxf(t.z, 0.2f * t.z); t.w = fmaxf(t.w, 0.2f * t.w);
            lo = t;
            mx.x = fmaxf(mx.x, lo.x); mx.y = fmaxf(mx.y, lo.y);
            mx.z = fmaxf(mx.z, lo.z); mx.w = fmaxf(mx.w, lo.w);
        }
        s_e[wid][nsub][0 * 68 + j] = lo.x;
        s_e[wid][nsub][1 * 68 + j] = lo.y;
        s_e[wid][nsub][2 * 68 + j] = lo.z;
        s_e[wid][nsub][3 * 68 + j] = lo.w;
    }
    #pragma unroll
    for (int o = 1; o < 16; o <<= 1) {
        mx.x = fmaxf(mx.x, __shfl_xor(mx.x, o, 64));
        mx.y = fmaxf(mx.y, __shfl_xor(mx.y, o, 64));
        mx.z = fmaxf(mx.z, __shfl_xor(mx.z, o, 64));
        mx.w = fmaxf(mx.w, __shfl_xor(mx.w, o, 64));
    }
    // --- pass B: exp + denominator; store unnormalized e (zeros for j >= dg) ---
    float4 den = make_float4(0.f, 0.f, 0.f, 0.f);
    for (int base = 0; base < dg16; base += 16) {
        int j = base + j0;
        float4 e = make_float4(0.f, 0.f, 0.f, 0.f);
        if (j < dg) {
            e.x = expf(s_e[wid][nsub][0 * 68 + j] - mx.x);
            e.y = expf(s_e[wid][nsub][1 * 68 + j] - mx.y);
            e.z = expf(s_e[wid][nsub][2 * 68 + j] - mx.z);
            e.w = expf(s_e[wid][nsub][3 * 68 + j] - mx.w);
        }
        den.x += e.x; den.y += e.y; den.z += e.z; den.w += e.w;
        s_e[wid][nsub][0 * 68 + j] = e.x;
        s_e[wid][nsub][1 * 68 + j] = e.y;
        s_e[wid][nsub][2 * 68 + j] = e.z;
        s_e[wid][nsub][3 * 68 + j] = e.w;
    }
    #pragma unroll
    for (int o = 1; o < 16; o <<= 1) {
        den.x += __shfl_xor(den.x, o, 64);
        den.y += __shfl_xor(den.y, o, 64);
        den.z += __shfl_xor(den.z, o, 64);
        den.w += __shfl_xor(den.w, o, 64);
    }
    if (j0 == 0) {
        s_den[wid][nsub][0] = den.x;
        s_den[wid][nsub][1] = den.y;
        s_den[wid][nsub][2] = den.z;
        s_den[wid][nsub][3] = den.w;
    }

    // --- gather phase: lane = head*16 + c4; x-row gathers, all nodes before epilogue ---
    int head = lane >> 4, c4 = lane & 15;
    const float4* xg = x4 + (size_t)g * NNODE * 16 + c4;
    float4 acc[4];
    #pragma unroll
    for (int nn = 0; nn < 4; nn++) acc[nn] = make_float4(0.f, 0.f, 0.f, 0.f);
    #pragma unroll
    for (int nn = 0; nn < 4; nn++) {
        int dgc = __shfl(dgp, nn * 16, 64);
        const float* ep = &s_e[wid][nn][head * 68];
        const int* sp = &s_src[wid][nn][0];
        for (int q = 0; q < dgc; q += 8) {
            int sj[8]; float av[8];
            #pragma unroll
            for (int u = 0; u < 8; u++) {
                sj[u] = sp[q + u];
                av[u] = ep[q + u];
            }
            float4 xv[8];
            #pragma unroll
            for (int u = 0; u < 8; u++) xv[u] = xg[(size_t)sj[u] * 16];
            #pragma unroll
            for (int u = 0; u < 8; u++) {
                acc[nn].x += av[u] * xv[u].x;
                acc[nn].y += av[u] * xv[u].y;
                acc[nn].z += av[u] * xv[u].z;
                acc[nn].w += av[u] * xv[u].w;
            }
        }
    }
    #pragma unroll
    for (int nn = 0; nn < 4; nn++) {
        float inv = 1.f / (s_den[wid][nn][head] + 1e-16f);
        float4 a = acc[nn];
        a.x *= inv; a.y *= inv; a.z *= inv; a.w *= inv;
        y4[((size_t)g * NNODE + n0 + nn) * 64 + lane] = a;   // y[n][h*64+c] as float4
    }
}

// ---------------- y @ W' full-K GEMM: 1000 blocks x 64 rows x 64 cols, bias+ELU+ls/ld fused ----------------
// kk chunk ck (64 kk) == head ck exactly. Thread = 4 rows x 4 cols.
__global__ __launch_bounds__(256) void k_ygemm3(const float4* __restrict__ y4, const float* __restrict__ W,
                                                const float* __restrict__ bg, float* __restrict__ xout,
                                                const float4* __restrict__ wa4, const float4* __restrict__ wd4,
                                                float4* __restrict__ ls4, float4* __restrict__ ld4) {
    __shared__ float ys[64 * 68];     // [kk_local][row], pitch 68
    int tid = threadIdx.x;
    int r0 = blockIdx.x * 64;
    int rg = tid >> 4;                // 0..15 -> rows rg*4..+3
    int cg = tid & 15;                // 0..15 -> cols cg*4..+3
    float acc[4][4];
    #pragma unroll
    for (int i = 0; i < 4; i++)
        #pragma unroll
        for (int j = 0; j < 4; j++) acc[i][j] = 0.f;

    int srow = tid & 63;
    int kq0 = tid >> 6;               // 0..3
    for (int ck = 0; ck < 4; ck++) {
        __syncthreads();
        #pragma unroll
        for (int it = 0; it < 4; it++) {
            int kq = kq0 + 4 * it;    // 0..15
            float4 v = y4[(size_t)(r0 + srow) * 64 + ck * 16 + kq];
            int k = kq * 4;
            ys[(k + 0) * 68 + srow] = v.x;
            ys[(k + 1) * 68 + srow] = v.y;
            ys[(k + 2) * 68 + srow] = v.z;
            ys[(k + 3) * 68 + srow] = v.w;
        }
        __syncthreads();
        const float* wp = W + ck * 64 + cg * 4;       // row c, head ck, cols cg*4..+3
        for (int kk = 0; kk < 64; kk++) {
            float4 w = *reinterpret_cast<const float4*>(&wp[(size_t)kk * HCOL]);
            float4 yv = *reinterpret_cast<const float4*>(&ys[kk * 68 + rg * 4]);
            float yr[4] = {yv.x, yv.y, yv.z, yv.w};
            #pragma unroll
            for (int i = 0; i < 4; i++) {
                acc[i][0] += yr[i] * w.x; acc[i][1] += yr[i] * w.y;
                acc[i][2] += yr[i] * w.z; acc[i][3] += yr[i] * w.w;
            }
        }
    }
    float4 bb = *reinterpret_cast<const float4*>(&bg[cg * 4]);
    float bv[4] = {bb.x, bb.y, bb.z, bb.w};
    #pragma unroll
    for (int i = 0; i < 4; i++) {
        int row = r0 + rg * 4 + i;
        float r[4];
        #pragma unroll
        for (int j = 0; j < 4; j++) {
            float v = acc[i][j] * 0.25f + bv[j];
            r[j] = v > 0.f ? v : expm1f(v);
        }
        *reinterpret_cast<float4*>(&xout[(size_t)row * HID + cg * 4]) =
            make_float4(r[0], r[1], r[2], r[3]);
        if (wa4) {
            float4 pls = make_float4(0.f, 0.f, 0.f, 0.f);
            float4 pld = make_float4(0.f, 0.f, 0.f, 0.f);
            #pragma unroll
            for (int jj = 0; jj < 4; jj++) {
                float4 wa_j = wa4[cg * 4 + jj];
                float4 wd_j = wd4[cg * 4 + jj];
                pls.x += r[jj] * wa_j.x; pls.y += r[jj] * wa_j.y;
                pls.z += r[jj] * wa_j.z; pls.w += r[jj] * wa_j.w;
                pld.x += r[jj] * wd_j.x; pld.y += r[jj] * wd_j.y;
                pld.z += r[jj] * wd_j.z; pld.w += r[jj] * wd_j.w;
            }
            #pragma unroll
            for (int o = 1; o < 16; o <<= 1) {
                pls.x += __shfl_xor(pls.x, o, 64); pls.y += __shfl_xor(pls.y, o, 64);
                pls.z += __shfl_xor(pls.z, o, 64); pls.w += __shfl_xor(pls.w, o, 64);
                pld.x += __shfl_xor(pld.x, o, 64); pld.y += __shfl_xor(pld.y, o, 64);
                pld.z += __shfl_xor(pld.z, o, 64); pld.w += __shfl_xor(pld.w, o, 64);
            }
            if (cg == 0) {
                ls4[row] = pls;
                ld4[row] = pld;
            }
        }
    }
}

// ---------------- GRU input GEMM: 500 K-slices, full 64x192 tile/block, no atomics ----------------
__global__ __launch_bounds__(256) void k_gi_gemm(const float* __restrict__ x, const float* __restrict__ W_ih,
                                                 float* __restrict__ gip) {
    __shared__ float xs[32 * 68];    // [kk][row], pitch 68
    __shared__ float ws[32 * 196];   // [kk][col 0..191], pitch 196
    int k0 = blockIdx.x * GIK;
    int tid = threadIdx.x;
    int lane = tid & 63;
    int wv = tid >> 6;
    int tx = tid & 15, ty = tid >> 4;
    float4 accs[4][3];
    #pragma unroll
    for (int i = 0; i < 4; i++)
        #pragma unroll
        for (int j = 0; j < 3; j++) accs[i][j] = make_float4(0.f, 0.f, 0.f, 0.f);

    for (int kt = 0; kt < GIK / 32; kt++) {
        int kb = k0 + kt * 32;
        #pragma unroll
        for (int it = 0; it < 2; it++) {
            int kq = wv + 4 * it;
            float4 v = *reinterpret_cast<const float4*>(&x[(size_t)lane * KGI + kb + kq * 4]);
            int k = kq * 4;
            xs[(k + 0) * 68 + lane] = v.x;
            xs[(k + 1) * 68 + lane] = v.y;
            xs[(k + 2) * 68 + lane] = v.z;
            xs[(k + 3) * 68 + lane] = v.w;
        }
        #pragma unroll
        for (int cg = 0; cg < 3; cg++) {
            #pragma unroll
            for (int it = 0; it < 2; it++) {
                int kq = wv + 4 * it;
                int c = cg * 64 + lane;
                float4 v = *reinterpret_cast<const float4*>(&W_ih[(size_t)c * KGI + kb + kq * 4]);
                int k = kq * 4;
                ws[(k + 0) * 196 + c] = v.x;
                ws[(k + 1) * 196 + c] = v.y;
                ws[(k + 2) * 196 + c] = v.z;
                ws[(k + 3) * 196 + c] = v.w;
            }
        }
        __syncthreads();
        for (int kk = 0; kk < 32; kk++) {
            float4 xv = *reinterpret_cast<const float4*>(&xs[kk * 68 + ty * 4]);
            float4 w0 = *reinterpret_cast<const float4*>(&ws[kk * 196 + tx * 4]);
            float4 w1 = *reinterpret_cast<const float4*>(&ws[kk * 196 + 64 + tx * 4]);
            float4 w2 = *reinterpret_cast<const float4*>(&ws[kk * 196 + 128 + tx * 4]);
            #pragma unroll
            for (int i = 0; i < 4; i++) {
                float xi = (i == 0) ? xv.x : (i == 1) ? xv.y : (i == 2) ? xv.z : xv.w;
                accs[i][0].x += xi * w0.x; accs[i][0].y += xi * w0.y; accs[i][0].z += xi * w0.z; accs[i][0].w += xi * w0.w;
                accs[i][1].x += xi * w1.x; accs[i][1].y += xi * w1.y; accs[i][1].z += xi * w1.z; accs[i][1].w += xi * w1.w;
                accs[i][2].x += xi * w2.x; accs[i][2].y += xi * w2.y; accs[i][2].z += xi * w2.z; accs[i][2].w += xi * w2.w;
            }
        }
        __syncthreads();
    }
    float* out = gip + (size_t)blockIdx.x * GOSZ;
    #pragma unroll
    for (int i = 0; i < 4; i++)
        #pragma unroll
        for (int j = 0; j < 3; j++)
            *reinterpret_cast<float4*>(&out[(ty * 4 + i) * GOUT + j * 64 + tx * 4]) = accs[i][j];
}

__global__ void k_gi_reduce1(const float* __restrict__ gip, float* __restrict__ gip2) {
    int idx = blockIdx.x * 256 + threadIdx.x;     // 0..GOSZ-1
    const float* p = gip + (size_t)blockIdx.y * 50 * GOSZ + idx;
    float a = 0.f;
    #pragma unroll 5
    for (int s = 0; s < 50; s++) a += p[(size_t)s * GOSZ];
    gip2[blockIdx.y * GOSZ + idx] = a;
}

__global__ void k_gi_reduce2(const float* __restrict__ gip2, const float* __restrict__ b_ih,
                             float* __restrict__ gi) {
    int idx = blockIdx.x * 256 + threadIdx.x;
    float a = b_ih[idx % GOUT];
    #pragma unroll
    for (int y = 0; y < 10; y++) a += gip2[(size_t)y * GOSZ + idx];
    gi[idx] = a;
}

// ---------------- GRU scan: one block per batch, W_hh row in registers, LDS broadcast hs ----------------
__global__ __launch_bounds__(192) void k_gru(const float* __restrict__ gi, const float* __restrict__ W_hh,
                                             const float* __restrict__ b_hh, float* __restrict__ hT) {
    __shared__ float hs[64];
    __shared__ float gh[192];
    int j = threadIdx.x;      // 0..191
    int b = blockIdx.x;       // 0..3
    float wrow[64];
    #pragma unroll
    for (int q = 0; q < 16; q++) {
        float4 v = *reinterpret_cast<const float4*>(&W_hh[(size_t)j * 64 + q * 4]);
        wrow[q * 4 + 0] = v.x; wrow[q * 4 + 1] = v.y;
        wrow[q * 4 + 2] = v.z; wrow[q * 4 + 3] = v.w;
    }
    float bj = b_hh[j];
    if (j < 64) hs[j] = 0.f;
    __syncthreads();
    for (int t = 0; t < TT; t++) {
        float a0 = 0.f, a1 = 0.f, a2 = 0.f, a3 = 0.f;
        #pragma unroll
        for (int q = 0; q < 16; q++) {
            float4 h4 = *reinterpret_cast<const float4*>(&hs[q * 4]);   // broadcast read
            a0 += h4.x * wrow[q * 4 + 0];
            a1 += h4.y * wrow[q * 4 + 1];
            a2 += h4.z * wrow[q * 4 + 2];
            a3 += h4.w * wrow[q * 4 + 3];
        }
        gh[j] = bj + ((a0 + a1) + (a2 + a3));
        __syncthreads();
        if (j < 64) {
            int row = (b * TT + t) * GOUT;
            float ir = gi[row + j], iz = gi[row + 64 + j], in_ = gi[row + 128 + j];
            float r = 1.f / (1.f + expf(-(ir + gh[j])));
            float z = 1.f / (1.f + expf(-(iz + gh[64 + j])));
            float nv = tanhf(in_ + r * gh[128 + j]);
            hs[j] = (1.f - z) * nv + z * hs[j];
        }
        __syncthreads();
    }
    if (j < 64) hT[b * 64 + j] = hs[j];
}

// ---------------- final FC ----------------
__global__ void k_final(const float* __restrict__ hT, const float* __restrict__ W_fc,
                        const float* __restrict__ b_fc, float* __restrict__ out) {
    int idx = blockIdx.x * 256 + threadIdx.x;
    if (idx >= NB * NNODE) return;
    int b = idx / NNODE, n = idx % NNODE;
    float acc = b_fc[n];
    #pragma unroll
    for (int c = 0; c < HID; c++) acc += hT[b * HID + c] * W_fc[c * NNODE + n];
    out[idx] = acc;
}

extern "C" void kernel_launch(void* const* d_in, const int* in_sizes, int n_in,
                              void* d_out, int out_size, void* d_ws, size_t ws_size,
                              hipStream_t stream) {
    const float* x_seq  = (const float*)d_in[0];
    const int*   eidx   = (const int*)  d_in[1];
    // d_in[2] edge_weight: unused by GATConv
    const float* W_in   = (const float*)d_in[3];
    const float* b_in   = (const float*)d_in[4];
    const float* Wg     = (const float*)d_in[5];
    const float* a_src  = (const float*)d_in[6];
    const float* a_dst  = (const float*)d_in[7];
    const float* bg     = (const float*)d_in[8];
    const float* W_ih   = (const float*)d_in[9];
    const float* W_hh   = (const float*)d_in[10];
    const float* b_ih   = (const float*)d_in[11];
    const float* b_hh   = (const float*)d_in[12];
    const float* W_fc   = (const float*)d_in[13];
    const float* b_fc   = (const float*)d_in[14];
    float* out = (float*)d_out;

    float* wsf = (float*)d_ws;
    size_t off = 0;
    float* x0     = wsf + off; off += (size_t)ROWS * HID;       // 4,096,000
    float* ybuf   = wsf + off; off += (size_t)ROWS * HCOL;      // 16,384,000
    float* lsb    = wsf + off; off += (size_t)ROWS * HEADS;     // 256,000
    float* ldb    = wsf + off; off += (size_t)ROWS * HEADS;     // 256,000
    float* wab    = wsf + off; off += NL * HCOL;                // 1,280
    float* wdb    = wsf + off; off += NL * HCOL;                // 1,280
    float* gib    = wsf + off; off += GOSZ;                     // 12,288
    float* hTb    = wsf + off; off += 256;
    int* ib = (int*)(wsf + off);
    int* src_e    = ib;          ib += EP;
    int* dst_e    = ib;          ib += EP;
    int* rowptr_p = ib;          ib += NNODE + 1;
    int* csr_src  = ib;          ib += EPAD;
    int* deg      = ib;          ib += NNODE;
    int* fill     = ib;          ib += NNODE;

    // gi partials alias ybuf (dead after GAT layers): (500+10)*12288 floats << 16.38M
    float* gip  = ybuf;
    float* gip2 = ybuf + (size_t)KSPLIT * GOSZ;

    k_build_edges<<<(EP + 255) / 256, 256, 0, stream>>>(eidx, src_e, dst_e, deg, fill);
    k_csr_count<<<(EP + 255) / 256, 256, 0, stream>>>(dst_e, deg);
    k_csr_scan<<<1, 256, 0, stream>>>(deg, rowptr_p);
    k_csr_fill<<<(EP + 255) / 256, 256, 0, stream>>>(src_e, dst_e, rowptr_p, fill, csr_src);
    k_pad_fill<<<(NNODE + 255) / 256, 256, 0, stream>>>(rowptr_p, deg, csr_src);

    k_wa<<<10, 256, 0, stream>>>(Wg, a_src, a_dst, wab, wdb);

    k_input_fc<<<ROWS * 16 / 256, 256, 0, stream>>>(
        x_seq, (const float4*)W_in, (const float4*)b_in,
        (const float4*)wab, (const float4*)wdb, (float4*)x0, (float4*)lsb, (float4*)ldb);

    for (int l = 0; l < NL; l++) {
        k_aggx<<<ROWS / 16, 256, 0, stream>>>(
            (const float4*)x0, (const float4*)lsb, (const float4*)ldb, rowptr_p, csr_src, deg,
            (float4*)ybuf);
        const float4* wa_next = (l + 1 < NL) ? (const float4*)(wab + (size_t)(l + 1) * HCOL) : nullptr;
        const float4* wd_next = (l + 1 < NL) ? (const float4*)(wdb + (size_t)(l + 1) * HCOL) : nullptr;
        k_ygemm3<<<ROWS / 64, 256, 0, stream>>>(
            (const float4*)ybuf, Wg + (size_t)l * HID * HCOL, bg + (size_t)l * HID, x0,
            wa_next, wd_next, (float4*)lsb, (float4*)ldb);
    }

    k_gi_gemm<<<KSPLIT, 256, 0, stream>>>(x0, W_ih, gip);
    k_gi_reduce1<<<dim3(GOSZ / 256, 10), 256, 0, stream>>>(gip, gip2);
    k_gi_reduce2<<<GOSZ / 256, 256, 0, stream>>>(gip2, b_ih, gib);
    k_gru<<<4, 192, 0, stream>>>(gib, W_hh, b_hh, hTb);
    k_final<<<(NB * NNODE + 255) / 256, 256, 0, stream>>>(hTb, W_fc, b_fc, out);
}